// Round 6
// baseline (2581.783 us; speedup 1.0000x reference)
//
#include <hip/hip_runtime.h>
#include <hip/hip_bf16.h>

// T=5 B=512 NA=16 S=64 A=16 HID=64 H=4 FD=256 LAT=128 N=8192 FIN=80
// Edge graph per batch: complete incl self-loops -> every dst aggregates all 16
// srcs of its batch; edge_index ignored (deterministic).
// seq = x[::16] -> layer-1 aggregation only for agent-0 dst.
// feat = ctx[:,-1] -> attention query only at t=4; the "+1 causal mask" is
// constant across all 5 keys at q=4 -> cancels in softmax.
//
// DTYPES (final, established rounds 0-5): inputs fp32 (reference dtypes),
// OUTPUT fp32 (reference returns float32; the "bf16" in the harness assert
// label is a hard-coded f-string literal, not a dtype indicator). Rounds 2/3/5
// failed identically because bf16 ushorts were written into the float32 d_out:
// readback float[i] ~= my[2i+1] -> plausible-scale decorrelated values,
// absmax 0.223 independent of compute path. ws use: 2.5 MB (fp32 seq).

__device__ __forceinline__ float wave_sum64(float v) {
    #pragma unroll
    for (int off = 32; off > 0; off >>= 1) v += __shfl_xor(v, off, 64);
    return v;
}
__device__ __forceinline__ float wave_max64(float v) {
    #pragma unroll
    for (int off = 32; off > 0; off >>= 1) v = fmaxf(v, __shfl_xor(v, off, 64));
    return v;
}
// dot of fp32 LDS vector (len 256) with fp32 global row
__device__ __forceinline__ float dotrow(const float* __restrict__ x,
                                        const float* __restrict__ wrow) {
    const float4* w4 = (const float4*)wrow;
    float acc = 0.f;
    #pragma unroll
    for (int i = 0; i < 64; i++) {
        float4 d = w4[i];
        const float* f = x + i * 4;
        acc = fmaf(d.x, f[0], acc);
        acc = fmaf(d.y, f[1], acc);
        acc = fmaf(d.z, f[2], acc);
        acc = fmaf(d.w, f[3], acc);
    }
    return acc;
}

// ------------------------- fused 2-layer GAT (VALU, fp32) -------------------
// One block per (b,t); 256 threads; thread = output column o; wave = head.
__global__ __launch_bounds__(256) void k_gat(
    const float* __restrict__ sig,   // (T,B,64)
    const float* __restrict__ nact,  // (T,B,256)
    const float* __restrict__ w0,    // (256,80)
    const float* __restrict__ as0, const float* __restrict__ ad0,
    const float* __restrict__ b0,
    const float* __restrict__ w1,    // (256,256)
    const float* __restrict__ as1, const float* __restrict__ ad1,
    const float* __restrict__ b1,
    float* __restrict__ seqf)        // (2560,256) fp32
{
    __shared__ __align__(16) float feats[16][80];
    __shared__ __align__(16) float xs[16][256];
    __shared__ __align__(16) float x1s[16][256];
    __shared__ float alphaf[4][16][16];       // [h][dst j][src s]
    __shared__ float es0L[16][4], ed0L[16][4], es1L[16][4], ed1L[16][4];
    __shared__ float alpha1f[4][16];

    const int tid = threadIdx.x;
    const int bt = blockIdx.x;
    const int b = bt / 5, t = bt - b * 5;
    const int o = tid, w = tid >> 6, lane = tid & 63;

    // node features: [0,64) = signals (agent 0 only), [64,80) = own action
    for (int idx = tid; idx < 16 * 80; idx += 256) {
        int m = idx / 80, k = idx - m * 80;
        float v;
        if (k < 64) v = (m == 0) ? sig[(t * 512 + b) * 64 + k] : 0.0f;
        else        v = nact[(t * 512 + b) * 256 + m * 16 + (k - 64)];
        feats[m][k] = v;
    }
    __syncthreads();

    // layer-0 GEMM: xl0[m][o] = sum_k feats[m][k] * w0[o][k]   (K=80)
    float acc0[16];
    #pragma unroll
    for (int m = 0; m < 16; m++) acc0[m] = 0.f;
    {
        const float4* w0r = (const float4*)(w0 + o * 80);  // 320B rows, 16B-aligned
        #pragma unroll
        for (int kc = 0; kc < 5; kc++) {
            float4 wq[4];
            #pragma unroll
            for (int q = 0; q < 4; q++) wq[q] = w0r[kc * 4 + q];
            #pragma unroll
            for (int m = 0; m < 16; m++) {
                #pragma unroll
                for (int q = 0; q < 4; q++) {
                    float4 xv = *(const float4*)&feats[m][kc * 16 + q * 4];
                    acc0[m] = fmaf(wq[q].x, xv.x, acc0[m]);
                    acc0[m] = fmaf(wq[q].y, xv.y, acc0[m]);
                    acc0[m] = fmaf(wq[q].z, xv.z, acc0[m]);
                    acc0[m] = fmaf(wq[q].w, xv.w, acc0[m]);
                }
            }
        }
    }
    // es0/ed0 per (node m, head w): reduce over this wave's 64 columns
    {
        const float asv = as0[o];   // att_src0[h][c], o = h*64+c
        const float adv = ad0[o];
        #pragma unroll
        for (int m = 0; m < 16; m++) {
            float s = wave_sum64(acc0[m] * asv);
            float d = wave_sum64(acc0[m] * adv);
            if (lane == 0) { es0L[m][w] = s; ed0L[m][w] = d; }
            xs[m][o] = acc0[m];
        }
    }
    __syncthreads();

    // alpha0: (h,j) per thread; softmax over 16 srcs of leakyrelu(es+ed)
    if (tid < 64) {
        int h = tid >> 4, j = tid & 15;
        float ej = ed0L[j][h];
        float e[16], m = -1e30f;
        #pragma unroll
        for (int s = 0; s < 16; s++) {
            float x = es0L[s][h] + ej;
            x = (x >= 0.f) ? x : 0.2f * x;
            e[s] = x; m = fmaxf(m, x);
        }
        float sum = 0.f;
        #pragma unroll
        for (int s = 0; s < 16; s++) { e[s] = __expf(e[s] - m); sum += e[s]; }
        float inv = 1.f / sum;
        #pragma unroll
        for (int s = 0; s < 16; s++) alphaf[h][j][s] = e[s] * inv;
    }
    __syncthreads();

    // aggregation 0: x1[j][o] = relu(sum_s alpha[h][j][s]*xl0[s][o] + b0[o])
    {
        float xv[16];
        #pragma unroll
        for (int s = 0; s < 16; s++) xv[s] = xs[s][o];
        const float b0v = b0[o];
        #pragma unroll
        for (int j = 0; j < 16; j++) {
            float a = 0.f;
            #pragma unroll
            for (int s = 0; s < 16; s++) a = fmaf(alphaf[w][j][s], xv[s], a);
            x1s[j][o] = fmaxf(a + b0v, 0.f);
        }
    }
    __syncthreads();

    // layer-1 GEMM: xl1[m][o] = sum_k x1[m][k] * w1[o][k]   (K=256)
    float acc1[16];
    #pragma unroll
    for (int m = 0; m < 16; m++) acc1[m] = 0.f;
    {
        const float4* w1r = (const float4*)(w1 + o * 256);
        for (int kc = 0; kc < 16; kc++) {
            float4 wq[4];
            #pragma unroll
            for (int q = 0; q < 4; q++) wq[q] = w1r[kc * 4 + q];
            #pragma unroll
            for (int m = 0; m < 16; m++) {
                #pragma unroll
                for (int q = 0; q < 4; q++) {
                    float4 xv = *(const float4*)&x1s[m][kc * 16 + q * 4];
                    acc1[m] = fmaf(wq[q].x, xv.x, acc1[m]);
                    acc1[m] = fmaf(wq[q].y, xv.y, acc1[m]);
                    acc1[m] = fmaf(wq[q].z, xv.z, acc1[m]);
                    acc1[m] = fmaf(wq[q].w, xv.w, acc1[m]);
                }
            }
        }
    }
    // es1/ed1
    {
        const float asv = as1[o];
        const float adv = ad1[o];
        #pragma unroll
        for (int m = 0; m < 16; m++) {
            float s = wave_sum64(acc1[m] * asv);
            float d = wave_sum64(acc1[m] * adv);
            if (lane == 0) { es1L[m][w] = s; ed1L[m][w] = d; }
        }
    }
    __syncthreads();

    // alpha1 for dst agent 0 only
    if (tid < 4) {
        int h = tid;
        float ej = ed1L[0][h];
        float e[16], m = -1e30f;
        #pragma unroll
        for (int s = 0; s < 16; s++) {
            float x = es1L[s][h] + ej;
            x = (x >= 0.f) ? x : 0.2f * x;
            e[s] = x; m = fmaxf(m, x);
        }
        float sum = 0.f;
        #pragma unroll
        for (int s = 0; s < 16; s++) { e[s] = __expf(e[s] - m); sum += e[s]; }
        float inv = 1.f / sum;
        #pragma unroll
        for (int s = 0; s < 16; s++) alpha1f[h][s] = e[s] * inv;
    }
    __syncthreads();

    // seq[bt][o] = relu(sum_s alpha1[h][s]*xl1[s][o] + b1[o])  (from registers)
    {
        float sv = 0.f;
        #pragma unroll
        for (int s = 0; s < 16; s++) sv = fmaf(alpha1f[w][s], acc1[s], sv);
        sv = fmaxf(sv + b1[o], 0.f);
        seqf[bt * 256 + o] = sv;
    }
}

// ------------------------- fused stage 2: qkv+attn+out_proj+heads -----------
// One block per batch b. All intermediates in LDS; only seqf read from ws.
__global__ __launch_bounds__(256) void k_stage2(
    const float* __restrict__ seqf,  // (2560,256) fp32
    const float* __restrict__ wip,   // (768,256)
    const float* __restrict__ bip,   // (768)
    const float* __restrict__ wop, const float* __restrict__ bop,
    const float* __restrict__ wm,  const float* __restrict__ bm,
    const float* __restrict__ wlv, const float* __restrict__ blv,
    const float* __restrict__ wb,  const float* __restrict__ bb,
    float* __restrict__ out)         // fp32! mean|logvar|belief concat
{
    __shared__ __align__(16) float sseq[5][256];
    __shared__ __align__(16) float kL[5][256], vL[5][256], qL[256];
    __shared__ __align__(16) float ctxL[256], featL[256];
    const int b = blockIdx.x, tid = threadIdx.x, o = tid;

    for (int i = tid; i < 1280; i += 256) {
        int t = i >> 8, c = i & 255;
        sseq[t][c] = seqf[(b * 5 + t) * 256 + c];
    }
    __syncthreads();

    // qkv: k,v for all t; q only at t=4
    #pragma unroll
    for (int t = 0; t < 5; t++) {
        kL[t][o] = dotrow(sseq[t], wip + (256 + o) * 256) + bip[256 + o];
        vL[t][o] = dotrow(sseq[t], wip + (512 + o) * 256) + bip[512 + o];
    }
    qL[o] = dotrow(sseq[4], wip + o * 256) + bip[o];
    __syncthreads();

    // attention at q=4 (mask constant over keys -> cancels); wave = head
    {
        const int h = tid >> 6, c = tid & 63, col = h * 64 + c;
        float q4 = qL[col];
        float sc[5];
        #pragma unroll
        for (int t = 0; t < 5; t++)
            sc[t] = wave_sum64(q4 * kL[t][col]) * 0.125f;   // /sqrt(64)
        float m = sc[0];
        #pragma unroll
        for (int t = 1; t < 5; t++) m = fmaxf(m, sc[t]);
        float p[5], sum = 0.f;
        #pragma unroll
        for (int t = 0; t < 5; t++) { p[t] = __expf(sc[t] - m); sum += p[t]; }
        float inv = 1.f / sum, cv = 0.f;
        #pragma unroll
        for (int t = 0; t < 5; t++) cv = fmaf(p[t], vL[t][col], cv);
        ctxL[col] = cv * inv;
    }
    __syncthreads();

    // out_proj
    featL[o] = dotrow(ctxL, wop + o * 256) + bop[o];
    __syncthreads();

    // heads: threads 0-127 mean, 128-255 logvar, then wave 0 belief softmax
    if (tid < 128) {
        out[b * 128 + tid] = dotrow(featL, wm + tid * 256) + bm[tid];
    } else {
        int j = tid - 128;
        out[65536 + b * 128 + j] = dotrow(featL, wlv + j * 256) + blv[j];
    }
    if (tid < 64) {
        float lg = dotrow(featL, wb + tid * 256) + bb[tid];
        float m = wave_max64(lg);
        float e = __expf(lg - m);
        float s = wave_sum64(e);
        out[131072 + b * 64 + tid] = e / s;
    }
}

// ---------------------------------------------------------------------------
extern "C" void kernel_launch(void* const* d_in, const int* in_sizes, int n_in,
                              void* d_out, int out_size, void* d_ws, size_t ws_size,
                              hipStream_t stream) {
    const float* sig  = (const float*)d_in[0];
    const float* nact = (const float*)d_in[1];
    const float* w0   = (const float*)d_in[2];
    const float* as0  = (const float*)d_in[3];
    const float* ad0  = (const float*)d_in[4];
    const float* b0   = (const float*)d_in[5];
    const float* w1   = (const float*)d_in[6];
    const float* as1  = (const float*)d_in[7];
    const float* ad1  = (const float*)d_in[8];
    const float* b1   = (const float*)d_in[9];
    const float* wip  = (const float*)d_in[10];
    const float* bip  = (const float*)d_in[11];
    const float* wop  = (const float*)d_in[12];
    const float* bop  = (const float*)d_in[13];
    const float* wm   = (const float*)d_in[14];
    const float* bm   = (const float*)d_in[15];
    const float* wlv  = (const float*)d_in[16];
    const float* blv  = (const float*)d_in[17];
    const float* wb   = (const float*)d_in[18];
    const float* bb   = (const float*)d_in[19];
    // d_in[20] = edge_index (deterministic complete graph) — unused.

    float* seqf = (float*)d_ws;   // 2560*256 fp32 = 2.5 MiB (only ws use)

    k_gat   <<<2560, 256, 0, stream>>>(sig, nact, w0, as0, ad0, b0,
                                       w1, as1, ad1, b1, seqf);
    k_stage2<<<512, 256, 0, stream>>>(seqf, wip, bip, wop, bop,
                                      wm, bm, wlv, blv, wb, bb,
                                      (float*)d_out);
}

// Round 7
// 296.469 us; speedup vs baseline: 8.7084x; 8.7084x over previous
//
#include <hip/hip_runtime.h>
#include <hip/hip_bf16.h>

// T=5 B=512 NA=16 S=64 A=16 HID=64 H=4 FD=256 LAT=128 N=8192 FIN=80
// Edge graph per batch: complete incl self-loops -> every dst aggregates all 16
// srcs of its batch; edge_index ignored (deterministic).
// seq = x[::16] -> layer-1 aggregation only for agent-0 dst.
// feat = ctx[:,-1] -> attention query only at t=4 (causal "+1 mask" constant
// there -> cancels in softmax).
// DTYPES: inputs fp32, output fp32 (established R0-R6).
//
// R7: k_gat GEMMs -> split-precision bf16 MFMA (x = hi + lo, 3 MFMAs:
// Ah*Bh + Ah*Bl + Al*Bh, err ~2^-17 = fp32-grade). Weights pre-split once
// into ws. R6's k_gat spilled (VGPR=256, WRITE_SIZE 2GB for 2.5MB of output);
// MFMA fragments keep VGPR ~100. k_stage2: load each k/v weight row once for
// all 5 t; bounded unrolls. ws total 2.98 MB (< 8.27 MB proven safe).

typedef short short8 __attribute__((ext_vector_type(8)));
typedef float floatx4 __attribute__((ext_vector_type(4)));

__device__ __forceinline__ float bf2f(unsigned short u) {
    return __uint_as_float(((unsigned int)u) << 16);
}
__device__ __forceinline__ unsigned short f2bf(float f) {
    unsigned int u = __float_as_uint(f);
    u = (u + 0x7fffu + ((u >> 16) & 1u)) >> 16;   // RNE
    return (unsigned short)u;
}
__device__ __forceinline__ float wave_sum64(float v) {
    #pragma unroll
    for (int off = 32; off > 0; off >>= 1) v += __shfl_xor(v, off, 64);
    return v;
}
__device__ __forceinline__ float wave_max64(float v) {
    #pragma unroll
    for (int off = 32; off > 0; off >>= 1) v = fmaxf(v, __shfl_xor(v, off, 64));
    return v;
}
// K=256 dot: fp32 LDS vector vs fp32 global row; bounded unroll (no spills)
__device__ __forceinline__ float dot256(const float* __restrict__ x,
                                        const float* __restrict__ wrow) {
    const float4* w4 = (const float4*)wrow;
    float acc = 0.f;
    #pragma unroll 8
    for (int i = 0; i < 64; i++) {
        float4 d = w4[i];
        float4 f = *(const float4*)(x + i * 4);
        acc = fmaf(d.x, f.x, acc);
        acc = fmaf(d.y, f.y, acc);
        acc = fmaf(d.z, f.z, acc);
        acc = fmaf(d.w, f.w, acc);
    }
    return acc;
}

// ---------------- prologue: split w0 (pad K 80->96) and w1 into bf16 hi/lo --
__global__ __launch_bounds__(256) void k_wconv(
    const float* __restrict__ w0, const float* __restrict__ w1,
    unsigned short* __restrict__ w0hi, unsigned short* __restrict__ w0lo,
    unsigned short* __restrict__ w1hi, unsigned short* __restrict__ w1lo)
{
    int i = blockIdx.x * 256 + threadIdx.x;   // 352*256 = 90112 exact
    if (i < 24576) {                          // w0 padded: [256][96]
        int n = i / 96, k = i - n * 96;
        float v = (k < 80) ? w0[n * 80 + k] : 0.f;
        unsigned short h = f2bf(v);
        w0hi[i] = h; w0lo[i] = f2bf(v - bf2f(h));
    } else {                                  // w1: [256][256]
        int j = i - 24576;
        float v = w1[j];
        unsigned short h = f2bf(v);
        w1hi[j] = h; w1lo[j] = f2bf(v - bf2f(h));
    }
}

// ---------------- fused 2-layer GAT: split-bf16 MFMA GEMMs, fp32 softmax ----
// One block per (b,t); 4 waves; wave w = head w (output cols w*64..w*64+63).
// MFMA 16x16x32 bf16. Layouts (m89/m91-verified): A[m=lane&15][k=quad*8+j],
// B^T[n=lane&15][k=quad*8+j], D col(n)=lane&15, row(m)=quad*4+reg.
__global__ __launch_bounds__(256) void k_gat(
    const float* __restrict__ sig,   // (T,B,64)
    const float* __restrict__ nact,  // (T,B,256)
    const unsigned short* __restrict__ w0hi, const unsigned short* __restrict__ w0lo,
    const float* __restrict__ as0, const float* __restrict__ ad0,
    const float* __restrict__ b0,
    const unsigned short* __restrict__ w1hi, const unsigned short* __restrict__ w1lo,
    const float* __restrict__ as1, const float* __restrict__ ad1,
    const float* __restrict__ b1,
    float* __restrict__ seqf)        // (2560,256) fp32
{
    __shared__ __align__(16) unsigned short fahi[16 * 96], falo[16 * 96];
    __shared__ __align__(16) float xs[16][256];            // xl0 fp32
    __shared__ __align__(16) unsigned short x1hi[16 * 256], x1lo[16 * 256];
    __shared__ float alphaf[4][16][16];                    // [h][dst j][src s]
    __shared__ float es0L[16][4], ed0L[16][4], es1L[16][4], ed1L[16][4];
    __shared__ float alpha1f[4][16];

    const int tid = threadIdx.x;
    const int bt = blockIdx.x;
    const int b = bt / 5, t = bt - b * 5;
    const int w = tid >> 6, lane = tid & 63, quad = lane >> 4, l16 = lane & 15;

    // 1. node features -> hi/lo bf16 (16 nodes x 96 k, pad 80..96 = 0)
    for (int i = tid; i < 16 * 96; i += 256) {
        int m = i / 96, k = i - m * 96;
        float v = 0.f;
        if (k < 64) { if (m == 0) v = sig[(t * 512 + b) * 64 + k]; }
        else if (k < 80) v = nact[(t * 512 + b) * 256 + m * 16 + (k - 64)];
        unsigned short h = f2bf(v);
        fahi[i] = h; falo[i] = f2bf(v - bf2f(h));
    }
    __syncthreads();

    // 2. layer-0 GEMM (K=96): xl0[m][n] = sum_k feats[m][k] * w0[n][k]
    short8 a0h[3], a0l[3];
    #pragma unroll
    for (int kt = 0; kt < 3; kt++) {
        a0h[kt] = *(const short8*)(fahi + l16 * 96 + kt * 32 + quad * 8);
        a0l[kt] = *(const short8*)(falo + l16 * 96 + kt * 32 + quad * 8);
    }
    floatx4 acc0[4];
    #pragma unroll
    for (int nt = 0; nt < 4; nt++) acc0[nt] = (floatx4){0.f, 0.f, 0.f, 0.f};
    #pragma unroll
    for (int nt = 0; nt < 4; nt++) {
        const int n = w * 64 + nt * 16 + l16;
        const unsigned short* bh = w0hi + n * 96;
        const unsigned short* bl = w0lo + n * 96;
        #pragma unroll
        for (int kt = 0; kt < 3; kt++) {
            short8 bhv = *(const short8*)(bh + kt * 32 + quad * 8);
            short8 blv = *(const short8*)(bl + kt * 32 + quad * 8);
            acc0[nt] = __builtin_amdgcn_mfma_f32_16x16x32_bf16(a0h[kt], bhv, acc0[nt], 0, 0, 0);
            acc0[nt] = __builtin_amdgcn_mfma_f32_16x16x32_bf16(a0h[kt], blv, acc0[nt], 0, 0, 0);
            acc0[nt] = __builtin_amdgcn_mfma_f32_16x16x32_bf16(a0l[kt], bhv, acc0[nt], 0, 0, 0);
        }
    }
    // es0/ed0 per (m, head w): partial over this lane's 4 n's, butterfly l16
    {
        float ps[4] = {0, 0, 0, 0}, pd[4] = {0, 0, 0, 0};
        #pragma unroll
        for (int nt = 0; nt < 4; nt++) {
            const int n = w * 64 + nt * 16 + l16;
            float av = as0[n], dv = ad0[n];
            #pragma unroll
            for (int r = 0; r < 4; r++) {
                ps[r] = fmaf(acc0[nt][r], av, ps[r]);
                pd[r] = fmaf(acc0[nt][r], dv, pd[r]);
                xs[quad * 4 + r][n] = acc0[nt][r];
            }
        }
        #pragma unroll
        for (int off = 1; off < 16; off <<= 1) {
            #pragma unroll
            for (int r = 0; r < 4; r++) {
                ps[r] += __shfl_xor(ps[r], off, 64);
                pd[r] += __shfl_xor(pd[r], off, 64);
            }
        }
        if (l16 == 0) {
            #pragma unroll
            for (int r = 0; r < 4; r++) {
                es0L[quad * 4 + r][w] = ps[r];
                ed0L[quad * 4 + r][w] = pd[r];
            }
        }
    }
    __syncthreads();

    // 3. alpha0: (h,j) per thread; softmax over 16 srcs of leakyrelu(es+ed)
    if (tid < 64) {
        int h = tid >> 4, j = tid & 15;
        float ej = ed0L[j][h];
        float e[16], m = -1e30f;
        #pragma unroll
        for (int s = 0; s < 16; s++) {
            float x = es0L[s][h] + ej;
            x = (x >= 0.f) ? x : 0.2f * x;
            e[s] = x; m = fmaxf(m, x);
        }
        float sum = 0.f;
        #pragma unroll
        for (int s = 0; s < 16; s++) { e[s] = __expf(e[s] - m); sum += e[s]; }
        float inv = 1.f / sum;
        #pragma unroll
        for (int s = 0; s < 16; s++) alphaf[h][j][s] = e[s] * inv;
    }
    __syncthreads();

    // 4. aggregation 0 (fp32 VALU): x1[j][o] = relu(sum_s alpha*xs + b0) -> hi/lo
    {
        const int o = tid;
        float xv[16];
        #pragma unroll
        for (int s = 0; s < 16; s++) xv[s] = xs[s][o];
        const float b0v = b0[o];
        #pragma unroll
        for (int j = 0; j < 16; j++) {
            float a = 0.f;
            #pragma unroll
            for (int s4 = 0; s4 < 4; s4++) {
                float4 al = *(const float4*)&alphaf[w][j][s4 * 4];
                a = fmaf(al.x, xv[s4 * 4 + 0], a);
                a = fmaf(al.y, xv[s4 * 4 + 1], a);
                a = fmaf(al.z, xv[s4 * 4 + 2], a);
                a = fmaf(al.w, xv[s4 * 4 + 3], a);
            }
            float v = fmaxf(a + b0v, 0.f);
            unsigned short h = f2bf(v);
            x1hi[j * 256 + o] = h;
            x1lo[j * 256 + o] = f2bf(v - bf2f(h));
        }
    }
    __syncthreads();

    // 5. layer-1 GEMM (K=256): xl1[m][n] = sum_k x1[m][k] * w1[n][k]
    floatx4 acc1[4];
    #pragma unroll
    for (int nt = 0; nt < 4; nt++) acc1[nt] = (floatx4){0.f, 0.f, 0.f, 0.f};
    #pragma unroll
    for (int kt = 0; kt < 8; kt++) {
        short8 ah = *(const short8*)(x1hi + l16 * 256 + kt * 32 + quad * 8);
        short8 al = *(const short8*)(x1lo + l16 * 256 + kt * 32 + quad * 8);
        #pragma unroll
        for (int nt = 0; nt < 4; nt++) {
            const int n = w * 64 + nt * 16 + l16;
            short8 bhv = *(const short8*)(w1hi + n * 256 + kt * 32 + quad * 8);
            short8 blv = *(const short8*)(w1lo + n * 256 + kt * 32 + quad * 8);
            acc1[nt] = __builtin_amdgcn_mfma_f32_16x16x32_bf16(ah, bhv, acc1[nt], 0, 0, 0);
            acc1[nt] = __builtin_amdgcn_mfma_f32_16x16x32_bf16(ah, blv, acc1[nt], 0, 0, 0);
            acc1[nt] = __builtin_amdgcn_mfma_f32_16x16x32_bf16(al, bhv, acc1[nt], 0, 0, 0);
        }
    }
    // es1/ed1
    {
        float ps[4] = {0, 0, 0, 0}, pd[4] = {0, 0, 0, 0};
        #pragma unroll
        for (int nt = 0; nt < 4; nt++) {
            const int n = w * 64 + nt * 16 + l16;
            float av = as1[n], dv = ad1[n];
            #pragma unroll
            for (int r = 0; r < 4; r++) {
                ps[r] = fmaf(acc1[nt][r], av, ps[r]);
                pd[r] = fmaf(acc1[nt][r], dv, pd[r]);
            }
        }
        #pragma unroll
        for (int off = 1; off < 16; off <<= 1) {
            #pragma unroll
            for (int r = 0; r < 4; r++) {
                ps[r] += __shfl_xor(ps[r], off, 64);
                pd[r] += __shfl_xor(pd[r], off, 64);
            }
        }
        if (l16 == 0) {
            #pragma unroll
            for (int r = 0; r < 4; r++) {
                es1L[quad * 4 + r][w] = ps[r];
                ed1L[quad * 4 + r][w] = pd[r];
            }
        }
    }
    __syncthreads();

    // 6. alpha1 for dst agent 0 only
    if (tid < 4) {
        int h = tid;
        float ej = ed1L[0][h];
        float e[16], m = -1e30f;
        #pragma unroll
        for (int s = 0; s < 16; s++) {
            float x = es1L[s][h] + ej;
            x = (x >= 0.f) ? x : 0.2f * x;
            e[s] = x; m = fmaxf(m, x);
        }
        float sum = 0.f;
        #pragma unroll
        for (int s = 0; s < 16; s++) { e[s] = __expf(e[s] - m); sum += e[s]; }
        float inv = 1.f / sum;
        #pragma unroll
        for (int s = 0; s < 16; s++) alpha1f[h][s] = e[s] * inv;
    }
    __syncthreads();

    // 7. seq[bt][n] = relu(sum_m alpha1[w][m]*xl1[m][n] + b1[n]) from regs
    {
        float av4[4];
        #pragma unroll
        for (int r = 0; r < 4; r++) av4[r] = alpha1f[w][quad * 4 + r];
        #pragma unroll
        for (int nt = 0; nt < 4; nt++) {
            float part = 0.f;
            #pragma unroll
            for (int r = 0; r < 4; r++) part = fmaf(acc1[nt][r], av4[r], part);
            part += __shfl_xor(part, 16, 64);
            part += __shfl_xor(part, 32, 64);
            if (quad == 0) {
                int n = w * 64 + nt * 16 + l16;
                seqf[bt * 256 + n] = fmaxf(part + b1[n], 0.f);
            }
        }
    }
}

// ---------------- fused stage 2: qkv + attention + out_proj + heads ---------
// One block per batch b. k/v weight rows loaded ONCE for all 5 t (R6 read 5x).
__global__ __launch_bounds__(256) void k_stage2(
    const float* __restrict__ seqf,  // (2560,256)
    const float* __restrict__ wip,   // (768,256): q|k|v rows
    const float* __restrict__ bip,
    const float* __restrict__ wop, const float* __restrict__ bop,
    const float* __restrict__ wm,  const float* __restrict__ bm,
    const float* __restrict__ wlv, const float* __restrict__ blv,
    const float* __restrict__ wb,  const float* __restrict__ bb,
    float* __restrict__ out)         // fp32: mean|logvar|belief concat
{
    __shared__ __align__(16) float sseq[5][256];
    __shared__ __align__(16) float kL[5][256], vL[5][256], qL[256];
    __shared__ __align__(16) float ctxL[256], featL[256];
    const int b = blockIdx.x, tid = threadIdx.x, o = tid;

    for (int i = tid; i < 1280; i += 256)
        sseq[i >> 8][i & 255] = seqf[b * 1280 + i];
    __syncthreads();

    // qkv: one pass over K; each weight row fetched once
    {
        const float4* wq4 = (const float4*)(wip + o * 256);
        const float4* wk4 = (const float4*)(wip + (256 + o) * 256);
        const float4* wv4 = (const float4*)(wip + (512 + o) * 256);
        float acck[5] = {0, 0, 0, 0, 0}, accv[5] = {0, 0, 0, 0, 0}, accq = 0.f;
        #pragma unroll 2
        for (int i = 0; i < 64; i++) {
            float4 wk = wk4[i], wv = wv4[i], wq = wq4[i];
            #pragma unroll
            for (int t = 0; t < 5; t++) {
                float4 st = *(const float4*)&sseq[t][i * 4];
                acck[t] = fmaf(wk.x, st.x, acck[t]);
                acck[t] = fmaf(wk.y, st.y, acck[t]);
                acck[t] = fmaf(wk.z, st.z, acck[t]);
                acck[t] = fmaf(wk.w, st.w, acck[t]);
                accv[t] = fmaf(wv.x, st.x, accv[t]);
                accv[t] = fmaf(wv.y, st.y, accv[t]);
                accv[t] = fmaf(wv.z, st.z, accv[t]);
                accv[t] = fmaf(wv.w, st.w, accv[t]);
                if (t == 4) {
                    accq = fmaf(wq.x, st.x, accq);
                    accq = fmaf(wq.y, st.y, accq);
                    accq = fmaf(wq.z, st.z, accq);
                    accq = fmaf(wq.w, st.w, accq);
                }
            }
        }
        #pragma unroll
        for (int t = 0; t < 5; t++) {
            kL[t][o] = acck[t] + bip[256 + o];
            vL[t][o] = accv[t] + bip[512 + o];
        }
        qL[o] = accq + bip[o];
    }
    __syncthreads();

    // attention at q=4 (mask constant over keys -> cancels); wave = head
    {
        const int h = tid >> 6, c = tid & 63, col = h * 64 + c;
        float q4 = qL[col];
        float sc[5];
        #pragma unroll
        for (int t = 0; t < 5; t++)
            sc[t] = wave_sum64(q4 * kL[t][col]) * 0.125f;   // /sqrt(64)
        float m = sc[0];
        #pragma unroll
        for (int t = 1; t < 5; t++) m = fmaxf(m, sc[t]);
        float p[5], sum = 0.f;
        #pragma unroll
        for (int t = 0; t < 5; t++) { p[t] = __expf(sc[t] - m); sum += p[t]; }
        float inv = 1.f / sum, cv = 0.f;
        #pragma unroll
        for (int t = 0; t < 5; t++) cv = fmaf(p[t], vL[t][col], cv);
        ctxL[col] = cv * inv;
    }
    __syncthreads();

    // out_proj
    featL[o] = dot256(ctxL, wop + o * 256) + bop[o];
    __syncthreads();

    // heads: threads 0-127 mean, 128-255 logvar; wave 0 also belief softmax
    if (tid < 128) {
        out[b * 128 + tid] = dot256(featL, wm + tid * 256) + bm[tid];
    } else {
        int j = tid - 128;
        out[65536 + b * 128 + j] = dot256(featL, wlv + j * 256) + blv[j];
    }
    if (tid < 64) {
        float lg = dot256(featL, wb + tid * 256) + bb[tid];
        float m = wave_max64(lg);
        float e = __expf(lg - m);
        float s = wave_sum64(e);
        out[131072 + b * 64 + tid] = e / s;
    }
}

// ---------------------------------------------------------------------------
extern "C" void kernel_launch(void* const* d_in, const int* in_sizes, int n_in,
                              void* d_out, int out_size, void* d_ws, size_t ws_size,
                              hipStream_t stream) {
    const float* sig  = (const float*)d_in[0];
    const float* nact = (const float*)d_in[1];
    const float* w0   = (const float*)d_in[2];
    const float* as0  = (const float*)d_in[3];
    const float* ad0  = (const float*)d_in[4];
    const float* b0   = (const float*)d_in[5];
    const float* w1   = (const float*)d_in[6];
    const float* as1  = (const float*)d_in[7];
    const float* ad1  = (const float*)d_in[8];
    const float* b1   = (const float*)d_in[9];
    const float* wip  = (const float*)d_in[10];
    const float* bip  = (const float*)d_in[11];
    const float* wop  = (const float*)d_in[12];
    const float* bop  = (const float*)d_in[13];
    const float* wm   = (const float*)d_in[14];
    const float* bm   = (const float*)d_in[15];
    const float* wlv  = (const float*)d_in[16];
    const float* blv  = (const float*)d_in[17];
    const float* wb   = (const float*)d_in[18];
    const float* bb   = (const float*)d_in[19];
    // d_in[20] = edge_index (deterministic complete graph) — unused.

    // ws layout (2,981,888 B total; <= 8.27 MB proven safe):
    float* seqf = (float*)d_ws;                          // 2560*256 fp32
    unsigned short* wcv = (unsigned short*)(seqf + 655360);
    unsigned short* w0hi = wcv;                          // 24576 (256x96)
    unsigned short* w0lo = wcv + 24576;
    unsigned short* w1hi = wcv + 49152;                  // 65536 (256x256)
    unsigned short* w1lo = wcv + 114688;

    k_wconv <<<352, 256, 0, stream>>>(w0, w1, w0hi, w0lo, w1hi, w1lo);
    k_gat   <<<2560, 256, 0, stream>>>(sig, nact, w0hi, w0lo, as0, ad0, b0,
                                       w1hi, w1lo, as1, ad1, b1, seqf);
    k_stage2<<<512, 256, 0, stream>>>(seqf, wip, bip, wop, bop,
                                      wm, bm, wlv, blv, wb, bb,
                                      (float*)d_out);
}

// Round 8
// 272.754 us; speedup vs baseline: 9.4656x; 1.0869x over previous
//
#include <hip/hip_runtime.h>
#include <hip/hip_bf16.h>

// T=5 B=512 NA=16 S=64 A=16 HID=64 H=4 FD=256 LAT=128 N=8192 FIN=80
// Edge graph per batch: complete incl self-loops -> every dst aggregates all
// 16 srcs of its batch; edge_index ignored. seq = x[::16] -> layer-1 agg only
// for agent-0 dst. feat = ctx[:,-1] -> attention query only at t=4 (causal
// "+1 mask" constant there -> cancels). Inputs fp32, output fp32 (R0-R6).
//
// R8 vs R7 (which passed at 296 us, k_gat 118 us):
//  - k_gat was latency-bound: 28.8% occupancy (LDS 44.5KB -> 3 blocks/CU) and
//    5.4M LDS bank conflicts (x1 stride 256 ushorts = 128 dwords == 0 mod 32
//    -> 16-way on GEMM1 A-frag reads; fa stride 96 -> 8-way).
//    Fix: LDS overlays (alpha over dead feats; x1 over dead xs) -> 24.8 KB
//    -> 6 blocks/CU; pad strides fa 104 / x1 264 / xs 257 -> 2-way (free).
//  - k_stage2: 768 threads (thread = (q|k|v, col)), weight row loaded once,
//    deeper unroll -> more loads in flight; 24 waves/CU.

typedef short short8 __attribute__((ext_vector_type(8)));
typedef float floatx4 __attribute__((ext_vector_type(4)));

__device__ __forceinline__ float bf2f(unsigned short u) {
    return __uint_as_float(((unsigned int)u) << 16);
}
__device__ __forceinline__ unsigned short f2bf(float f) {
    unsigned int u = __float_as_uint(f);
    u = (u + 0x7fffu + ((u >> 16) & 1u)) >> 16;   // RNE
    return (unsigned short)u;
}
__device__ __forceinline__ float wave_sum64(float v) {
    #pragma unroll
    for (int off = 32; off > 0; off >>= 1) v += __shfl_xor(v, off, 64);
    return v;
}
__device__ __forceinline__ float wave_max64(float v) {
    #pragma unroll
    for (int off = 32; off > 0; off >>= 1) v = fmaxf(v, __shfl_xor(v, off, 64));
    return v;
}
// K=256 dot: fp32 LDS vector vs fp32 global row
__device__ __forceinline__ float dot256(const float* __restrict__ x,
                                        const float* __restrict__ wrow) {
    const float4* w4 = (const float4*)wrow;
    float acc = 0.f;
    #pragma unroll 8
    for (int i = 0; i < 64; i++) {
        float4 d = w4[i];
        float4 f = *(const float4*)(x + i * 4);
        acc = fmaf(d.x, f.x, acc);
        acc = fmaf(d.y, f.y, acc);
        acc = fmaf(d.z, f.z, acc);
        acc = fmaf(d.w, f.w, acc);
    }
    return acc;
}

// ---------------- prologue: split w0 (pad K 80->96) and w1 into bf16 hi/lo --
__global__ __launch_bounds__(256) void k_wconv(
    const float* __restrict__ w0, const float* __restrict__ w1,
    unsigned short* __restrict__ w0hi, unsigned short* __restrict__ w0lo,
    unsigned short* __restrict__ w1hi, unsigned short* __restrict__ w1lo)
{
    int i = blockIdx.x * 256 + threadIdx.x;   // 352*256 = 90112 exact
    if (i < 24576) {                          // w0 padded: [256][96]
        int n = i / 96, k = i - n * 96;
        float v = (k < 80) ? w0[n * 80 + k] : 0.f;
        unsigned short h = f2bf(v);
        w0hi[i] = h; w0lo[i] = f2bf(v - bf2f(h));
    } else {                                  // w1: [256][256]
        int j = i - 24576;
        float v = w1[j];
        unsigned short h = f2bf(v);
        w1hi[j] = h; w1lo[j] = f2bf(v - bf2f(h));
    }
}

// ---------------- fused 2-layer GAT: split-bf16 MFMA GEMMs, fp32 softmax ----
// One block per (b,t); 4 waves; wave w = head w (output cols w*64..w*64+63).
// MFMA 16x16x32 bf16: A[m=lane&15][k=quad*8+j], B^T[n=lane&15][k=quad*8+j],
// D col(n)=lane&15, row(m)=quad*4+reg.
// LDS overlays (24832 B total -> 6 blocks/CU):
//   region A [0,6656): fa_hi(16x104), fa_lo; later alphaf[4][16][16] f32
//   region B [6656,23552): xs f32 [16][257]; later x1hi/x1lo [16][264]
//   region C [23552,24832): es0/ed0/es1/ed1 [16][4] f32, alpha1f [4][16]
__global__ __launch_bounds__(256) void k_gat(
    const float* __restrict__ sig,   // (T,B,64)
    const float* __restrict__ nact,  // (T,B,256)
    const unsigned short* __restrict__ w0hi, const unsigned short* __restrict__ w0lo,
    const float* __restrict__ as0, const float* __restrict__ ad0,
    const float* __restrict__ b0,
    const unsigned short* __restrict__ w1hi, const unsigned short* __restrict__ w1lo,
    const float* __restrict__ as1, const float* __restrict__ ad1,
    const float* __restrict__ b1,
    float* __restrict__ seqf)        // (2560,256) fp32
{
    __shared__ __align__(16) char smem[24832];
    unsigned short* fahi = (unsigned short*)smem;              // 16*104
    unsigned short* falo = fahi + 16 * 104;                    // 16*104
    float* alphaf = (float*)smem;                              // [4][16][16]
    float* xs     = (float*)(smem + 6656);                     // [16][257]
    unsigned short* x1hi = (unsigned short*)(smem + 6656);     // [16][264]
    unsigned short* x1lo = x1hi + 16 * 264;
    float* es0L = (float*)(smem + 23552);                      // [16][4]
    float* ed0L = es0L + 64;
    float* es1L = ed0L + 64;
    float* ed1L = es1L + 64;
    float* alpha1f = ed1L + 64;                                // [4][16]

    const int tid = threadIdx.x;
    const int bt = blockIdx.x;
    const int b = bt / 5, t = bt - b * 5;
    const int w = tid >> 6, lane = tid & 63, quad = lane >> 4, l16 = lane & 15;

    // 1. node features -> hi/lo bf16 (16 nodes x 96 valid k, stride 104)
    for (int i = tid; i < 16 * 104; i += 256) {
        int m = i / 104, k = i - m * 104;
        float v = 0.f;
        if (k < 64) { if (m == 0) v = sig[(t * 512 + b) * 64 + k]; }
        else if (k < 80) v = nact[(t * 512 + b) * 256 + m * 16 + (k - 64)];
        unsigned short h = f2bf(v);
        fahi[i] = h; falo[i] = f2bf(v - bf2f(h));
    }
    __syncthreads();

    // 2. layer-0 GEMM (K=96): xl0[m][n] = sum_k feats[m][k] * w0[n][k]
    short8 a0h[3], a0l[3];
    #pragma unroll
    for (int kt = 0; kt < 3; kt++) {
        a0h[kt] = *(const short8*)(fahi + l16 * 104 + kt * 32 + quad * 8);
        a0l[kt] = *(const short8*)(falo + l16 * 104 + kt * 32 + quad * 8);
    }
    floatx4 acc0[4];
    #pragma unroll
    for (int nt = 0; nt < 4; nt++) acc0[nt] = (floatx4){0.f, 0.f, 0.f, 0.f};
    #pragma unroll
    for (int nt = 0; nt < 4; nt++) {
        const int n = w * 64 + nt * 16 + l16;
        const unsigned short* bh = w0hi + n * 96;
        const unsigned short* bl = w0lo + n * 96;
        #pragma unroll
        for (int kt = 0; kt < 3; kt++) {
            short8 bhv = *(const short8*)(bh + kt * 32 + quad * 8);
            short8 blv = *(const short8*)(bl + kt * 32 + quad * 8);
            acc0[nt] = __builtin_amdgcn_mfma_f32_16x16x32_bf16(a0h[kt], bhv, acc0[nt], 0, 0, 0);
            acc0[nt] = __builtin_amdgcn_mfma_f32_16x16x32_bf16(a0h[kt], blv, acc0[nt], 0, 0, 0);
            acc0[nt] = __builtin_amdgcn_mfma_f32_16x16x32_bf16(a0l[kt], bhv, acc0[nt], 0, 0, 0);
        }
    }
    // es0/ed0 per (m, head w); xs[m][n] staged for aggregation
    {
        float ps[4] = {0, 0, 0, 0}, pd[4] = {0, 0, 0, 0};
        #pragma unroll
        for (int nt = 0; nt < 4; nt++) {
            const int n = w * 64 + nt * 16 + l16;
            float av = as0[n], dv = ad0[n];
            #pragma unroll
            for (int r = 0; r < 4; r++) {
                ps[r] = fmaf(acc0[nt][r], av, ps[r]);
                pd[r] = fmaf(acc0[nt][r], dv, pd[r]);
                xs[(quad * 4 + r) * 257 + n] = acc0[nt][r];
            }
        }
        #pragma unroll
        for (int off = 1; off < 16; off <<= 1) {
            #pragma unroll
            for (int r = 0; r < 4; r++) {
                ps[r] += __shfl_xor(ps[r], off, 64);
                pd[r] += __shfl_xor(pd[r], off, 64);
            }
        }
        if (l16 == 0) {
            #pragma unroll
            for (int r = 0; r < 4; r++) {
                es0L[(quad * 4 + r) * 4 + w] = ps[r];
                ed0L[(quad * 4 + r) * 4 + w] = pd[r];
            }
        }
    }
    __syncthreads();

    // 3. alpha0 -> overlays dead fa region
    if (tid < 64) {
        int h = tid >> 4, j = tid & 15;
        float ej = ed0L[j * 4 + h];
        float e[16], m = -1e30f;
        #pragma unroll
        for (int s = 0; s < 16; s++) {
            float x = es0L[s * 4 + h] + ej;
            x = (x >= 0.f) ? x : 0.2f * x;
            e[s] = x; m = fmaxf(m, x);
        }
        float sum = 0.f;
        #pragma unroll
        for (int s = 0; s < 16; s++) { e[s] = __expf(e[s] - m); sum += e[s]; }
        float inv = 1.f / sum;
        #pragma unroll
        for (int s = 0; s < 16; s++) alphaf[(h * 16 + j) * 16 + s] = e[s] * inv;
    }
    __syncthreads();

    // 4. aggregation 0: xv to regs, barrier, then x1 overlays dead xs region
    {
        const int o = tid;
        float xv[16];
        #pragma unroll
        for (int s = 0; s < 16; s++) xv[s] = xs[s * 257 + o];
        __syncthreads();                      // all xs reads done before overwrite
        const float b0v = b0[o];
        #pragma unroll
        for (int j = 0; j < 16; j++) {
            float a = 0.f;
            #pragma unroll
            for (int s = 0; s < 16; s++)
                a = fmaf(alphaf[(w * 16 + j) * 16 + s], xv[s], a);
            float v = fmaxf(a + b0v, 0.f);
            unsigned short h = f2bf(v);
            x1hi[j * 264 + o] = h;
            x1lo[j * 264 + o] = f2bf(v - bf2f(h));
        }
    }
    __syncthreads();

    // 5. layer-1 GEMM (K=256): xl1[m][n] = sum_k x1[m][k] * w1[n][k]
    floatx4 acc1[4];
    #pragma unroll
    for (int nt = 0; nt < 4; nt++) acc1[nt] = (floatx4){0.f, 0.f, 0.f, 0.f};
    #pragma unroll
    for (int kt = 0; kt < 8; kt++) {
        short8 ah = *(const short8*)(x1hi + l16 * 264 + kt * 32 + quad * 8);
        short8 al = *(const short8*)(x1lo + l16 * 264 + kt * 32 + quad * 8);
        #pragma unroll
        for (int nt = 0; nt < 4; nt++) {
            const int n = w * 64 + nt * 16 + l16;
            short8 bhv = *(const short8*)(w1hi + n * 256 + kt * 32 + quad * 8);
            short8 blv = *(const short8*)(w1lo + n * 256 + kt * 32 + quad * 8);
            acc1[nt] = __builtin_amdgcn_mfma_f32_16x16x32_bf16(ah, bhv, acc1[nt], 0, 0, 0);
            acc1[nt] = __builtin_amdgcn_mfma_f32_16x16x32_bf16(ah, blv, acc1[nt], 0, 0, 0);
            acc1[nt] = __builtin_amdgcn_mfma_f32_16x16x32_bf16(al, bhv, acc1[nt], 0, 0, 0);
        }
    }
    // es1/ed1
    {
        float ps[4] = {0, 0, 0, 0}, pd[4] = {0, 0, 0, 0};
        #pragma unroll
        for (int nt = 0; nt < 4; nt++) {
            const int n = w * 64 + nt * 16 + l16;
            float av = as1[n], dv = ad1[n];
            #pragma unroll
            for (int r = 0; r < 4; r++) {
                ps[r] = fmaf(acc1[nt][r], av, ps[r]);
                pd[r] = fmaf(acc1[nt][r], dv, pd[r]);
            }
        }
        #pragma unroll
        for (int off = 1; off < 16; off <<= 1) {
            #pragma unroll
            for (int r = 0; r < 4; r++) {
                ps[r] += __shfl_xor(ps[r], off, 64);
                pd[r] += __shfl_xor(pd[r], off, 64);
            }
        }
        if (l16 == 0) {
            #pragma unroll
            for (int r = 0; r < 4; r++) {
                es1L[(quad * 4 + r) * 4 + w] = ps[r];
                ed1L[(quad * 4 + r) * 4 + w] = pd[r];
            }
        }
    }
    __syncthreads();

    // 6. alpha1 for dst agent 0 only
    if (tid < 4) {
        int h = tid;
        float ej = ed1L[0 * 4 + h];
        float e[16], m = -1e30f;
        #pragma unroll
        for (int s = 0; s < 16; s++) {
            float x = es1L[s * 4 + h] + ej;
            x = (x >= 0.f) ? x : 0.2f * x;
            e[s] = x; m = fmaxf(m, x);
        }
        float sum = 0.f;
        #pragma unroll
        for (int s = 0; s < 16; s++) { e[s] = __expf(e[s] - m); sum += e[s]; }
        float inv = 1.f / sum;
        #pragma unroll
        for (int s = 0; s < 16; s++) alpha1f[h * 16 + s] = e[s] * inv;
    }
    __syncthreads();

    // 7. seq[bt][n] = relu(sum_m alpha1[w][m]*xl1[m][n] + b1[n]) from regs
    {
        float av4[4];
        #pragma unroll
        for (int r = 0; r < 4; r++) av4[r] = alpha1f[w * 16 + quad * 4 + r];
        #pragma unroll
        for (int nt = 0; nt < 4; nt++) {
            float part = 0.f;
            #pragma unroll
            for (int r = 0; r < 4; r++) part = fmaf(acc1[nt][r], av4[r], part);
            part += __shfl_xor(part, 16, 64);
            part += __shfl_xor(part, 32, 64);
            if (quad == 0) {
                int n = w * 64 + nt * 16 + l16;
                seqf[bt * 256 + n] = fmaxf(part + b1[n], 0.f);
            }
        }
    }
}

// ---------------- fused stage 2: qkv + attention + out_proj + heads ---------
// One block per batch b, 768 threads (12 waves): thread = (kind q|k|v, col).
__global__ __launch_bounds__(768) void k_stage2(
    const float* __restrict__ seqf,  // (2560,256)
    const float* __restrict__ wip,   // (768,256): q|k|v rows
    const float* __restrict__ bip,
    const float* __restrict__ wop, const float* __restrict__ bop,
    const float* __restrict__ wm,  const float* __restrict__ bm,
    const float* __restrict__ wlv, const float* __restrict__ blv,
    const float* __restrict__ wb,  const float* __restrict__ bb,
    float* __restrict__ out)         // fp32: mean|logvar|belief concat
{
    __shared__ __align__(16) float sseq[5][256];
    __shared__ __align__(16) float kL[5][256], vL[5][256], qL[256];
    __shared__ __align__(16) float ctxL[256], featL[256];
    const int b = blockIdx.x, tid = threadIdx.x;

    for (int i = tid; i < 1280; i += 768)
        sseq[i >> 8][i & 255] = seqf[b * 1280 + i];
    __syncthreads();

    // qkv: thread (kind,o); weight row loaded once; deep unroll for MLP
    {
        const int kind = tid >> 8, o = tid & 255;
        const float4* w4 = (const float4*)(wip + (kind * 256 + o) * 256);
        if (kind == 0) {                       // q at t=4 only
            float acc = 0.f;
            #pragma unroll 8
            for (int i = 0; i < 64; i++) {
                float4 d = w4[i];
                float4 s = *(const float4*)&sseq[4][i * 4];
                acc = fmaf(d.x, s.x, acc);
                acc = fmaf(d.y, s.y, acc);
                acc = fmaf(d.z, s.z, acc);
                acc = fmaf(d.w, s.w, acc);
            }
            qL[o] = acc + bip[o];
        } else {                               // k (kind=1) / v (kind=2), all t
            float acc[5] = {0, 0, 0, 0, 0};
            #pragma unroll 4
            for (int i = 0; i < 64; i++) {
                float4 d = w4[i];
                #pragma unroll
                for (int t = 0; t < 5; t++) {
                    float4 s = *(const float4*)&sseq[t][i * 4];
                    acc[t] = fmaf(d.x, s.x, acc[t]);
                    acc[t] = fmaf(d.y, s.y, acc[t]);
                    acc[t] = fmaf(d.z, s.z, acc[t]);
                    acc[t] = fmaf(d.w, s.w, acc[t]);
                }
            }
            float bv = bip[kind * 256 + o];
            float* dst = (kind == 1) ? &kL[0][0] : &vL[0][0];
            #pragma unroll
            for (int t = 0; t < 5; t++) dst[t * 256 + o] = acc[t] + bv;
        }
    }
    __syncthreads();

    // attention at q=4 (mask constant over keys -> cancels); waves 0-3 = heads
    if (tid < 256) {
        const int h = tid >> 6, c = tid & 63, col = h * 64 + c;
        float q4 = qL[col];
        float sc[5];
        #pragma unroll
        for (int t = 0; t < 5; t++)
            sc[t] = wave_sum64(q4 * kL[t][col]) * 0.125f;   // /sqrt(64)
        float m = sc[0];
        #pragma unroll
        for (int t = 1; t < 5; t++) m = fmaxf(m, sc[t]);
        float p[5], sum = 0.f;
        #pragma unroll
        for (int t = 0; t < 5; t++) { p[t] = __expf(sc[t] - m); sum += p[t]; }
        float inv = 1.f / sum, cv = 0.f;
        #pragma unroll
        for (int t = 0; t < 5; t++) cv = fmaf(p[t], vL[t][col], cv);
        ctxL[col] = cv * inv;
    }
    __syncthreads();

    // out_proj
    if (tid < 256)
        featL[tid] = dot256(ctxL, wop + tid * 256) + bop[tid];
    __syncthreads();

    // heads: 0-127 mean, 128-255 logvar, 256-319 belief (wave 4, lanes 0-63)
    if (tid < 128) {
        out[b * 128 + tid] = dot256(featL, wm + tid * 256) + bm[tid];
    } else if (tid < 256) {
        int j = tid - 128;
        out[65536 + b * 128 + j] = dot256(featL, wlv + j * 256) + blv[j];
    } else if (tid < 320) {
        int j = tid - 256;
        float lg = dot256(featL, wb + j * 256) + bb[j];
        float m = wave_max64(lg);
        float e = __expf(lg - m);
        float s = wave_sum64(e);
        out[131072 + b * 64 + j] = e / s;
    }
}

// ---------------------------------------------------------------------------
extern "C" void kernel_launch(void* const* d_in, const int* in_sizes, int n_in,
                              void* d_out, int out_size, void* d_ws, size_t ws_size,
                              hipStream_t stream) {
    const float* sig  = (const float*)d_in[0];
    const float* nact = (const float*)d_in[1];
    const float* w0   = (const float*)d_in[2];
    const float* as0  = (const float*)d_in[3];
    const float* ad0  = (const float*)d_in[4];
    const float* b0   = (const float*)d_in[5];
    const float* w1   = (const float*)d_in[6];
    const float* as1  = (const float*)d_in[7];
    const float* ad1  = (const float*)d_in[8];
    const float* b1   = (const float*)d_in[9];
    const float* wip  = (const float*)d_in[10];
    const float* bip  = (const float*)d_in[11];
    const float* wop  = (const float*)d_in[12];
    const float* bop  = (const float*)d_in[13];
    const float* wm   = (const float*)d_in[14];
    const float* bm   = (const float*)d_in[15];
    const float* wlv  = (const float*)d_in[16];
    const float* blv  = (const float*)d_in[17];
    const float* wb   = (const float*)d_in[18];
    const float* bb   = (const float*)d_in[19];
    // d_in[20] = edge_index (deterministic complete graph) — unused.

    // ws layout (2,981,888 B total; <= 8.27 MB proven safe):
    float* seqf = (float*)d_ws;                          // 2560*256 fp32
    unsigned short* wcv = (unsigned short*)(seqf + 655360);
    unsigned short* w0hi = wcv;                          // 24576 (256x96)
    unsigned short* w0lo = wcv + 24576;
    unsigned short* w1hi = wcv + 49152;                  // 65536 (256x256)
    unsigned short* w1lo = wcv + 114688;

    k_wconv <<<352, 256, 0, stream>>>(w0, w1, w0hi, w0lo, w1hi, w1lo);
    k_gat   <<<2560, 256, 0, stream>>>(sig, nact, w0hi, w0lo, as0, ad0, b0,
                                       w1hi, w1lo, as1, ad1, b1, seqf);
    k_stage2<<<512, 768, 0, stream>>>(seqf, wip, bip, wop, bop,
                                      wm, bm, wlv, blv, wb, bb,
                                      (float*)d_out);
}

// Round 9
// 270.696 us; speedup vs baseline: 9.5376x; 1.0076x over previous
//
#include <hip/hip_runtime.h>
#include <hip/hip_bf16.h>

// T=5 B=512 NA=16 S=64 A=16 HID=64 H=4 FD=256 LAT=128 N=8192 FIN=80
// Edge graph per batch: complete incl self-loops -> every dst aggregates all
// 16 srcs of its batch; edge_index ignored. seq = x[::16] -> layer-1 agg only
// for agent-0 dst. feat = ctx[:,-1] -> attention query only at t=4 (causal
// "+1 mask" constant there -> cancels). Inputs fp32, output fp32.
//
// R9 vs R8 (272.8 us; k_gat 111 us): R8 doubled occupancy (29->55%) for only
// -6% -> occupancy NOT binding. VGPR_Count=40 says the compiler minimized
// registers and cannot batch the ~88 scattered 16B weight loads/block; their
// L2 latency is serially exposed per phase (MfmaUtil 8 + VALUBusy 16 = 75%
// uncoverable stall). Fix: __launch_bounds__ min-waves to open the VGPR cap
// (k_gat (256,4) -> 128; k_stage2 (768,4) -> 128) + batch all W-fragment
// loads of a tile into registers before the MFMAs. Numerics unchanged.

typedef short short8 __attribute__((ext_vector_type(8)));
typedef float floatx4 __attribute__((ext_vector_type(4)));

__device__ __forceinline__ float bf2f(unsigned short u) {
    return __uint_as_float(((unsigned int)u) << 16);
}
__device__ __forceinline__ unsigned short f2bf(float f) {
    unsigned int u = __float_as_uint(f);
    u = (u + 0x7fffu + ((u >> 16) & 1u)) >> 16;   // RNE
    return (unsigned short)u;
}
__device__ __forceinline__ float wave_sum64(float v) {
    #pragma unroll
    for (int off = 32; off > 0; off >>= 1) v += __shfl_xor(v, off, 64);
    return v;
}
__device__ __forceinline__ float wave_max64(float v) {
    #pragma unroll
    for (int off = 32; off > 0; off >>= 1) v = fmaxf(v, __shfl_xor(v, off, 64));
    return v;
}
// K=256 dot: fp32 LDS vector vs fp32 global row; batched 8-deep loads
__device__ __forceinline__ float dot256(const float* __restrict__ x,
                                        const float* __restrict__ wrow) {
    const float4* w4 = (const float4*)wrow;
    float acc = 0.f;
    #pragma unroll
    for (int ii = 0; ii < 8; ii++) {
        float4 wreg[8];
        #pragma unroll
        for (int j = 0; j < 8; j++) wreg[j] = w4[ii * 8 + j];
        #pragma unroll
        for (int j = 0; j < 8; j++) {
            float4 f = *(const float4*)(x + (ii * 8 + j) * 4);
            acc = fmaf(wreg[j].x, f.x, acc);
            acc = fmaf(wreg[j].y, f.y, acc);
            acc = fmaf(wreg[j].z, f.z, acc);
            acc = fmaf(wreg[j].w, f.w, acc);
        }
    }
    return acc;
}

// ---------------- prologue: split w0 (pad K 80->96) and w1 into bf16 hi/lo --
__global__ __launch_bounds__(256) void k_wconv(
    const float* __restrict__ w0, const float* __restrict__ w1,
    unsigned short* __restrict__ w0hi, unsigned short* __restrict__ w0lo,
    unsigned short* __restrict__ w1hi, unsigned short* __restrict__ w1lo)
{
    int i = blockIdx.x * 256 + threadIdx.x;   // 352*256 = 90112 exact
    if (i < 24576) {                          // w0 padded: [256][96]
        int n = i / 96, k = i - n * 96;
        float v = (k < 80) ? w0[n * 80 + k] : 0.f;
        unsigned short h = f2bf(v);
        w0hi[i] = h; w0lo[i] = f2bf(v - bf2f(h));
    } else {                                  // w1: [256][256]
        int j = i - 24576;
        float v = w1[j];
        unsigned short h = f2bf(v);
        w1hi[j] = h; w1lo[j] = f2bf(v - bf2f(h));
    }
}

// ---------------- fused 2-layer GAT: split-bf16 MFMA GEMMs, fp32 softmax ----
// One block per (b,t); 4 waves; wave w = head w (output cols w*64..w*64+63).
// MFMA 16x16x32 bf16: A[m=lane&15][k=quad*8+j], B^T[n=lane&15][k=quad*8+j],
// D col(n)=lane&15, row(m)=quad*4+reg.
// LDS overlays (24832 B): fa(16x104 hi/lo) -> alphaf; xs[16][257] -> x1 hi/lo
// [16][264]; tail: es/ed/alpha1.
__global__ __launch_bounds__(256, 4) void k_gat(
    const float* __restrict__ sig,   // (T,B,64)
    const float* __restrict__ nact,  // (T,B,256)
    const unsigned short* __restrict__ w0hi, const unsigned short* __restrict__ w0lo,
    const float* __restrict__ as0, const float* __restrict__ ad0,
    const float* __restrict__ b0,
    const unsigned short* __restrict__ w1hi, const unsigned short* __restrict__ w1lo,
    const float* __restrict__ as1, const float* __restrict__ ad1,
    const float* __restrict__ b1,
    float* __restrict__ seqf)        // (2560,256) fp32
{
    __shared__ __align__(16) char smem[24832];
    unsigned short* fahi = (unsigned short*)smem;              // 16*104
    unsigned short* falo = fahi + 16 * 104;                    // 16*104
    float* alphaf = (float*)smem;                              // [4][16][16]
    float* xs     = (float*)(smem + 6656);                     // [16][257]
    unsigned short* x1hi = (unsigned short*)(smem + 6656);     // [16][264]
    unsigned short* x1lo = x1hi + 16 * 264;
    float* es0L = (float*)(smem + 23552);                      // [16][4]
    float* ed0L = es0L + 64;
    float* es1L = ed0L + 64;
    float* ed1L = es1L + 64;
    float* alpha1f = ed1L + 64;                                // [4][16]

    const int tid = threadIdx.x;
    const int bt = blockIdx.x;
    const int b = bt / 5, t = bt - b * 5;
    const int w = tid >> 6, lane = tid & 63, quad = lane >> 4, l16 = lane & 15;

    // 1. node features -> hi/lo bf16 (16 nodes x 96 valid k, stride 104)
    for (int i = tid; i < 16 * 104; i += 256) {
        int m = i / 104, k = i - m * 104;
        float v = 0.f;
        if (k < 64) { if (m == 0) v = sig[(t * 512 + b) * 64 + k]; }
        else if (k < 80) v = nact[(t * 512 + b) * 256 + m * 16 + (k - 64)];
        unsigned short h = f2bf(v);
        fahi[i] = h; falo[i] = f2bf(v - bf2f(h));
    }
    __syncthreads();

    // 2. layer-0 GEMM (K=96): xl0[m][n] = sum_k feats[m][k] * w0[n][k]
    short8 a0h[3], a0l[3];
    #pragma unroll
    for (int kt = 0; kt < 3; kt++) {
        a0h[kt] = *(const short8*)(fahi + l16 * 104 + kt * 32 + quad * 8);
        a0l[kt] = *(const short8*)(falo + l16 * 104 + kt * 32 + quad * 8);
    }
    floatx4 acc0[4];
    #pragma unroll
    for (int nt = 0; nt < 4; nt++) acc0[nt] = (floatx4){0.f, 0.f, 0.f, 0.f};
    #pragma unroll
    for (int nt = 0; nt < 4; nt++) {
        const int n = w * 64 + nt * 16 + l16;
        const unsigned short* bh = w0hi + n * 96;
        const unsigned short* bl = w0lo + n * 96;
        // batch all 6 W-fragment loads before the MFMAs (loads in flight)
        short8 bhv[3], blv[3];
        #pragma unroll
        for (int kt = 0; kt < 3; kt++) {
            bhv[kt] = *(const short8*)(bh + kt * 32 + quad * 8);
            blv[kt] = *(const short8*)(bl + kt * 32 + quad * 8);
        }
        #pragma unroll
        for (int kt = 0; kt < 3; kt++) {
            acc0[nt] = __builtin_amdgcn_mfma_f32_16x16x32_bf16(a0h[kt], bhv[kt], acc0[nt], 0, 0, 0);
            acc0[nt] = __builtin_amdgcn_mfma_f32_16x16x32_bf16(a0h[kt], blv[kt], acc0[nt], 0, 0, 0);
            acc0[nt] = __builtin_amdgcn_mfma_f32_16x16x32_bf16(a0l[kt], bhv[kt], acc0[nt], 0, 0, 0);
        }
    }
    // es0/ed0 per (m, head w); xs[m][n] staged for aggregation
    {
        float ps[4] = {0, 0, 0, 0}, pd[4] = {0, 0, 0, 0};
        #pragma unroll
        for (int nt = 0; nt < 4; nt++) {
            const int n = w * 64 + nt * 16 + l16;
            float av = as0[n], dv = ad0[n];
            #pragma unroll
            for (int r = 0; r < 4; r++) {
                ps[r] = fmaf(acc0[nt][r], av, ps[r]);
                pd[r] = fmaf(acc0[nt][r], dv, pd[r]);
                xs[(quad * 4 + r) * 257 + n] = acc0[nt][r];
            }
        }
        #pragma unroll
        for (int off = 1; off < 16; off <<= 1) {
            #pragma unroll
            for (int r = 0; r < 4; r++) {
                ps[r] += __shfl_xor(ps[r], off, 64);
                pd[r] += __shfl_xor(pd[r], off, 64);
            }
        }
        if (l16 == 0) {
            #pragma unroll
            for (int r = 0; r < 4; r++) {
                es0L[(quad * 4 + r) * 4 + w] = ps[r];
                ed0L[(quad * 4 + r) * 4 + w] = pd[r];
            }
        }
    }
    __syncthreads();

    // 3. alpha0 -> overlays dead fa region
    if (tid < 64) {
        int h = tid >> 4, j = tid & 15;
        float ej = ed0L[j * 4 + h];
        float e[16], m = -1e30f;
        #pragma unroll
        for (int s = 0; s < 16; s++) {
            float x = es0L[s * 4 + h] + ej;
            x = (x >= 0.f) ? x : 0.2f * x;
            e[s] = x; m = fmaxf(m, x);
        }
        float sum = 0.f;
        #pragma unroll
        for (int s = 0; s < 16; s++) { e[s] = __expf(e[s] - m); sum += e[s]; }
        float inv = 1.f / sum;
        #pragma unroll
        for (int s = 0; s < 16; s++) alphaf[(h * 16 + j) * 16 + s] = e[s] * inv;
    }
    __syncthreads();

    // 4. aggregation 0: xv to regs, barrier, then x1 overlays dead xs region
    {
        const int o = tid;
        float xv[16];
        #pragma unroll
        for (int s = 0; s < 16; s++) xv[s] = xs[s * 257 + o];
        __syncthreads();                      // all xs reads done before overwrite
        const float b0v = b0[o];
        #pragma unroll
        for (int j = 0; j < 16; j++) {
            float a = 0.f;
            #pragma unroll
            for (int s = 0; s < 16; s++)
                a = fmaf(alphaf[(w * 16 + j) * 16 + s], xv[s], a);
            float v = fmaxf(a + b0v, 0.f);
            unsigned short h = f2bf(v);
            x1hi[j * 264 + o] = h;
            x1lo[j * 264 + o] = f2bf(v - bf2f(h));
        }
    }
    __syncthreads();

    // 5. layer-1 GEMM (K=256): xl1[m][n] = sum_k x1[m][k] * w1[n][k]
    floatx4 acc1[4];
    #pragma unroll
    for (int nt = 0; nt < 4; nt++) acc1[nt] = (floatx4){0.f, 0.f, 0.f, 0.f};
    #pragma unroll
    for (int kt = 0; kt < 8; kt++) {
        // batch: 8 global W-frags (4 nt x hi/lo) + 2 LDS A-frags up front
        short8 bhv[4], blv[4];
        #pragma unroll
        for (int nt = 0; nt < 4; nt++) {
            const int n = w * 64 + nt * 16 + l16;
            bhv[nt] = *(const short8*)(w1hi + n * 256 + kt * 32 + quad * 8);
            blv[nt] = *(const short8*)(w1lo + n * 256 + kt * 32 + quad * 8);
        }
        short8 ah = *(const short8*)(x1hi + l16 * 264 + kt * 32 + quad * 8);
        short8 al = *(const short8*)(x1lo + l16 * 264 + kt * 32 + quad * 8);
        #pragma unroll
        for (int nt = 0; nt < 4; nt++) {
            acc1[nt] = __builtin_amdgcn_mfma_f32_16x16x32_bf16(ah, bhv[nt], acc1[nt], 0, 0, 0);
            acc1[nt] = __builtin_amdgcn_mfma_f32_16x16x32_bf16(ah, blv[nt], acc1[nt], 0, 0, 0);
            acc1[nt] = __builtin_amdgcn_mfma_f32_16x16x32_bf16(al, bhv[nt], acc1[nt], 0, 0, 0);
        }
    }
    // es1/ed1
    {
        float ps[4] = {0, 0, 0, 0}, pd[4] = {0, 0, 0, 0};
        #pragma unroll
        for (int nt = 0; nt < 4; nt++) {
            const int n = w * 64 + nt * 16 + l16;
            float av = as1[n], dv = ad1[n];
            #pragma unroll
            for (int r = 0; r < 4; r++) {
                ps[r] = fmaf(acc1[nt][r], av, ps[r]);
                pd[r] = fmaf(acc1[nt][r], dv, pd[r]);
            }
        }
        #pragma unroll
        for (int off = 1; off < 16; off <<= 1) {
            #pragma unroll
            for (int r = 0; r < 4; r++) {
                ps[r] += __shfl_xor(ps[r], off, 64);
                pd[r] += __shfl_xor(pd[r], off, 64);
            }
        }
        if (l16 == 0) {
            #pragma unroll
            for (int r = 0; r < 4; r++) {
                es1L[(quad * 4 + r) * 4 + w] = ps[r];
                ed1L[(quad * 4 + r) * 4 + w] = pd[r];
            }
        }
    }
    __syncthreads();

    // 6. alpha1 for dst agent 0 only
    if (tid < 4) {
        int h = tid;
        float ej = ed1L[0 * 4 + h];
        float e[16], m = -1e30f;
        #pragma unroll
        for (int s = 0; s < 16; s++) {
            float x = es1L[s * 4 + h] + ej;
            x = (x >= 0.f) ? x : 0.2f * x;
            e[s] = x; m = fmaxf(m, x);
        }
        float sum = 0.f;
        #pragma unroll
        for (int s = 0; s < 16; s++) { e[s] = __expf(e[s] - m); sum += e[s]; }
        float inv = 1.f / sum;
        #pragma unroll
        for (int s = 0; s < 16; s++) alpha1f[h * 16 + s] = e[s] * inv;
    }
    __syncthreads();

    // 7. seq[bt][n] = relu(sum_m alpha1[w][m]*xl1[m][n] + b1[n]) from regs
    {
        float av4[4];
        #pragma unroll
        for (int r = 0; r < 4; r++) av4[r] = alpha1f[w * 16 + quad * 4 + r];
        #pragma unroll
        for (int nt = 0; nt < 4; nt++) {
            float part = 0.f;
            #pragma unroll
            for (int r = 0; r < 4; r++) part = fmaf(acc1[nt][r], av4[r], part);
            part += __shfl_xor(part, 16, 64);
            part += __shfl_xor(part, 32, 64);
            if (quad == 0) {
                int n = w * 64 + nt * 16 + l16;
                seqf[bt * 256 + n] = fmaxf(part + b1[n], 0.f);
            }
        }
    }
}

// ---------------- fused stage 2: qkv + attention + out_proj + heads ---------
// One block per batch b, 768 threads (12 waves): thread = (kind q|k|v, col).
__global__ __launch_bounds__(768, 4) void k_stage2(
    const float* __restrict__ seqf,  // (2560,256)
    const float* __restrict__ wip,   // (768,256): q|k|v rows
    const float* __restrict__ bip,
    const float* __restrict__ wop, const float* __restrict__ bop,
    const float* __restrict__ wm,  const float* __restrict__ bm,
    const float* __restrict__ wlv, const float* __restrict__ blv,
    const float* __restrict__ wb,  const float* __restrict__ bb,
    float* __restrict__ out)         // fp32: mean|logvar|belief concat
{
    __shared__ __align__(16) float sseq[5][256];
    __shared__ __align__(16) float kL[5][256], vL[5][256], qL[256];
    __shared__ __align__(16) float ctxL[256], featL[256];
    const int b = blockIdx.x, tid = threadIdx.x;

    for (int i = tid; i < 1280; i += 768)
        sseq[i >> 8][i & 255] = seqf[b * 1280 + i];
    __syncthreads();

    // qkv: thread (kind,o); weight row loaded once, 8 float4 batched in regs
    {
        const int kind = tid >> 8, o = tid & 255;
        const float4* w4 = (const float4*)(wip + (kind * 256 + o) * 256);
        if (kind == 0) {                       // q at t=4 only
            qL[o] = dot256(&sseq[4][0], wip + o * 256) + bip[o];
        } else {                               // k (kind=1) / v (kind=2), all t
            float acc[5] = {0, 0, 0, 0, 0};
            #pragma unroll
            for (int ii = 0; ii < 8; ii++) {
                float4 wreg[8];
                #pragma unroll
                for (int j = 0; j < 8; j++) wreg[j] = w4[ii * 8 + j];
                #pragma unroll
                for (int j = 0; j < 8; j++) {
                    #pragma unroll
                    for (int t = 0; t < 5; t++) {
                        float4 s = *(const float4*)&sseq[t][(ii * 8 + j) * 4];
                        acc[t] = fmaf(wreg[j].x, s.x, acc[t]);
                        acc[t] = fmaf(wreg[j].y, s.y, acc[t]);
                        acc[t] = fmaf(wreg[j].z, s.z, acc[t]);
                        acc[t] = fmaf(wreg[j].w, s.w, acc[t]);
                    }
                }
            }
            float bv = bip[kind * 256 + o];
            float* dst = (kind == 1) ? &kL[0][0] : &vL[0][0];
            #pragma unroll
            for (int t = 0; t < 5; t++) dst[t * 256 + o] = acc[t] + bv;
        }
    }
    __syncthreads();

    // attention at q=4 (mask constant over keys -> cancels); waves 0-3 = heads
    if (tid < 256) {
        const int h = tid >> 6, c = tid & 63, col = h * 64 + c;
        float q4 = qL[col];
        float sc[5];
        #pragma unroll
        for (int t = 0; t < 5; t++)
            sc[t] = wave_sum64(q4 * kL[t][col]) * 0.125f;   // /sqrt(64)
        float m = sc[0];
        #pragma unroll
        for (int t = 1; t < 5; t++) m = fmaxf(m, sc[t]);
        float p[5], sum = 0.f;
        #pragma unroll
        for (int t = 0; t < 5; t++) { p[t] = __expf(sc[t] - m); sum += p[t]; }
        float inv = 1.f / sum, cv = 0.f;
        #pragma unroll
        for (int t = 0; t < 5; t++) cv = fmaf(p[t], vL[t][col], cv);
        ctxL[col] = cv * inv;
    }
    __syncthreads();

    // out_proj
    if (tid < 256)
        featL[tid] = dot256(ctxL, wop + tid * 256) + bop[tid];
    __syncthreads();

    // heads: 0-127 mean, 128-255 logvar, 256-319 belief (wave 4, lanes 0-63)
    if (tid < 128) {
        out[b * 128 + tid] = dot256(featL, wm + tid * 256) + bm[tid];
    } else if (tid < 256) {
        int j = tid - 128;
        out[65536 + b * 128 + j] = dot256(featL, wlv + j * 256) + blv[j];
    } else if (tid < 320) {
        int j = tid - 256;
        float lg = dot256(featL, wb + j * 256) + bb[j];
        float m = wave_max64(lg);
        float e = __expf(lg - m);
        float s = wave_sum64(e);
        out[131072 + b * 64 + j] = e / s;
    }
}

// ---------------------------------------------------------------------------
extern "C" void kernel_launch(void* const* d_in, const int* in_sizes, int n_in,
                              void* d_out, int out_size, void* d_ws, size_t ws_size,
                              hipStream_t stream) {
    const float* sig  = (const float*)d_in[0];
    const float* nact = (const float*)d_in[1];
    const float* w0   = (const float*)d_in[2];
    const float* as0  = (const float*)d_in[3];
    const float* ad0  = (const float*)d_in[4];
    const float* b0   = (const float*)d_in[5];
    const float* w1   = (const float*)d_in[6];
    const float* as1  = (const float*)d_in[7];
    const float* ad1  = (const float*)d_in[8];
    const float* b1   = (const float*)d_in[9];
    const float* wip  = (const float*)d_in[10];
    const float* bip  = (const float*)d_in[11];
    const float* wop  = (const float*)d_in[12];
    const float* bop  = (const float*)d_in[13];
    const float* wm   = (const float*)d_in[14];
    const float* bm   = (const float*)d_in[15];
    const float* wlv  = (const float*)d_in[16];
    const float* blv  = (const float*)d_in[17];
    const float* wb   = (const float*)d_in[18];
    const float* bb   = (const float*)d_in[19];
    // d_in[20] = edge_index (deterministic complete graph) — unused.

    // ws layout (2,981,888 B total):
    float* seqf = (float*)d_ws;                          // 2560*256 fp32
    unsigned short* wcv = (unsigned short*)(seqf + 655360);
    unsigned short* w0hi = wcv;                          // 24576 (256x96)
    unsigned short* w0lo = wcv + 24576;
    unsigned short* w1hi = wcv + 49152;                  // 65536 (256x256)
    unsigned short* w1lo = wcv + 114688;

    k_wconv <<<352, 256, 0, stream>>>(w0, w1, w0hi, w0lo, w1hi, w1lo);
    k_gat   <<<2560, 256, 0, stream>>>(sig, nact, w0hi, w0lo, as0, ad0, b0,
                                       w1hi, w1lo, as1, ad1, b1, seqf);
    k_stage2<<<512, 768, 0, stream>>>(seqf, wip, bip, wop, bop,
                                      wm, bm, wlv, blv, wb, bb,
                                      (float*)d_out);
}

// Round 11
// 236.324 us; speedup vs baseline: 10.9248x; 1.1454x over previous
//
#include <hip/hip_runtime.h>
#include <hip/hip_bf16.h>

// T=5 B=512 NA=16 S=64 A=16 HID=64 H=4 FD=256 LAT=128 N=8192 FIN=80
// Inputs fp32, output fp32. edge graph = complete per 16-agent batch (ignored
// input). seq = x[::16] (dst agent-0 only). attention query only at t=4.
//
// R11 = R10 with one bug fixed: k_stage2's sseq load split batches at i>>11
// (2048) instead of 1280, corrupting the second batch of every block (absmax
// 0.104 = half-wrong outputs). Now a flat copy. R10 design summary:
//  1. ALGEBRA: xl0[m] = (m==0)*S + act[m]*W0a  (S = sig@W0s, 16-dim act);
//     layer-1 GEMM collapses to per-head GEMV via z_h; es1/ed1 via u1/ud1 =
//     W1^T(att slices). Stage-1 FLOP/group: 5.3M -> 0.37M. All fp32, no MFMA.
//  2. LAYOUT: all weights transposed once into ws -> coalesced weight loads.
//  3. AMORTIZE: k_gat = 1 block per b (5 t-groups); k_stage2 = 2 batches/block.

__device__ __forceinline__ float wave_sum64(float v) {
    #pragma unroll
    for (int off = 32; off > 0; off >>= 1) v += __shfl_xor(v, off, 64);
    return v;
}
__device__ __forceinline__ float wave_max64(float v) {
    #pragma unroll
    for (int off = 32; off > 0; off >>= 1) v = fmaxf(v, __shfl_xor(v, off, 64));
    return v;
}

// ---------------- prologue 1: transposes into ws ----------------------------
// dst segments (float offsets within tws): W0sT[64][256] | W0aT[16][256] |
// W1T[256][256] | wipT[256][768] | wopT[256][256] | whT[256][320]
__global__ __launch_bounds__(256) void k_pre1(
    const float* __restrict__ w0, const float* __restrict__ w1,
    const float* __restrict__ wip, const float* __restrict__ wop,
    const float* __restrict__ wm, const float* __restrict__ wlv,
    const float* __restrict__ wb, float* __restrict__ tws)
{
    int i = blockIdx.x * 256 + threadIdx.x;      // 1680*256 = 430080 exact
    float v;
    if (i < 16384) {                             // W0sT[k][n] = w0[n][k]
        int k = i >> 8, n = i & 255;
        v = w0[n * 80 + k];
    } else if (i < 20480) {                      // W0aT[k][n] = w0[n][64+k]
        int j = i - 16384; int k = j >> 8, n = j & 255;
        v = w0[n * 80 + 64 + k];
    } else if (i < 86016) {                      // W1T[k][n] = w1[n][k]
        int j = i - 20480; int k = j >> 8, n = j & 255;
        v = w1[n * 256 + k];
    } else if (i < 282624) {                     // wipT[k][n'] = wip[n'][k]
        int j = i - 86016; int k = j / 768, n = j - k * 768;
        v = wip[n * 256 + k];
    } else if (i < 348160) {                     // wopT[k][n] = wop[n][k]
        int j = i - 282624; int k = j >> 8, n = j & 255;
        v = wop[n * 256 + k];
    } else {                                     // whT[k][j]: mean|logvar|belief
        int j = i - 348160; int k = j / 320, o = j - k * 320;
        if (o < 128)      v = wm[o * 256 + k];
        else if (o < 256) v = wlv[(o - 128) * 256 + k];
        else              v = wb[(o - 256) * 256 + k];
    }
    tws[i] = v;
}

// ---------------- prologue 2: u1/ud1 (4x256), pa0/pd0 (4x16) ----------------
__global__ __launch_bounds__(256) void k_pre2(
    const float* __restrict__ w0, const float* __restrict__ w1,
    const float* __restrict__ as0, const float* __restrict__ ad0,
    const float* __restrict__ as1, const float* __restrict__ ad1,
    float* __restrict__ u1, float* __restrict__ ud1,
    float* __restrict__ pa0, float* __restrict__ pd0)
{
    const int tid = threadIdx.x;
    // u1[h][k] = sum_c as1[h][c] * w1[(h*64+c)][k]; ud1 with ad1
    for (int q = 0; q < 4; q++) {
        int idx = q * 256 + tid;                 // 1024
        int h = idx >> 8, k = idx & 255;
        float su = 0.f, sd = 0.f;
        for (int c = 0; c < 64; c++) {
            float wv = w1[(h * 64 + c) * 256 + k];
            su = fmaf(as1[h * 64 + c], wv, su);
            sd = fmaf(ad1[h * 64 + c], wv, sd);
        }
        u1[idx] = su; ud1[idx] = sd;
    }
    // pa0[h][k<16] = sum_c as0[h][c] * w0[(h*64+c)][64+k]; pd0 with ad0
    if (tid < 64) {
        int h = tid >> 4, k = tid & 15;
        float su = 0.f, sd = 0.f;
        for (int c = 0; c < 64; c++) {
            float wv = w0[(h * 64 + c) * 80 + 64 + k];
            su = fmaf(as0[h * 64 + c], wv, su);
            sd = fmaf(ad0[h * 64 + c], wv, sd);
        }
        pa0[tid] = su; pd0[tid] = sd;
    }
}

// ---------------- stage 1: fused 2-layer GAT, one block per b ---------------
__global__ __launch_bounds__(256) void k_gat(
    const float* __restrict__ sig,   // (T,B,64)
    const float* __restrict__ nact,  // (T,B,256)
    const float* __restrict__ W0sT,  // [64][256]
    const float* __restrict__ W0aT,  // [16][256]
    const float* __restrict__ W1T,   // [256][256]
    const float* __restrict__ u1g, const float* __restrict__ ud1g,   // [4][256]
    const float* __restrict__ pa0g, const float* __restrict__ pd0g,  // [4][16]
    const float* __restrict__ as0, const float* __restrict__ ad0,
    const float* __restrict__ b0, const float* __restrict__ b1,
    float* __restrict__ seqf)        // (2560,256)
{
    __shared__ float sigL[5][64];
    __shared__ float actL[5][16][16];
    __shared__ float SL[5][258];
    __shared__ float u1L[4][256], ud1L[4][256];
    __shared__ float pa0L[64], pd0L[64];
    __shared__ float sSL[5][4], dSL[5][4];
    __shared__ float es0L[5][16][4], ed0L[5][16][4];
    __shared__ float a0g[4][16][16];             // per-group alpha0 [h][j][s]
    __shared__ float dL[4][16][16];              // per-group d [h][j][k]
    __shared__ float x1L[16][258];               // per-group x1
    __shared__ float espL[16][4][4];             // es1 partials [m][h][p]
    __shared__ float edpL[4][4];
    __shared__ float es1L[16][4];
    __shared__ float edL[4];
    __shared__ float alpha1L[4][16];
    __shared__ float zL[5][4][258];              // z per group/head

    const int tid = threadIdx.x;
    const int b = blockIdx.x;

    // ---- load inputs + precomputed small tensors
    for (int i = tid; i < 320; i += 256)
        sigL[i >> 6][i & 63] = sig[((i >> 6) * 512 + b) * 64 + (i & 63)];
    for (int i = tid; i < 1280; i += 256) {
        int g = i >> 8, r = i & 255;
        actL[g][r >> 4][r & 15] = nact[(g * 512 + b) * 256 + r];
    }
    for (int q = 0; q < 4; q++) {
        int idx = q * 256 + tid;
        u1L[idx >> 8][idx & 255] = u1g[idx];
        ud1L[idx >> 8][idx & 255] = ud1g[idx];
    }
    if (tid < 64) { pa0L[tid] = pa0g[tid]; pd0L[tid] = pd0g[tid]; }
    __syncthreads();

    // ---- S[g][n] = sum_k sig[g][k] * W0sT[k][n]  (coalesced W reads)
    {
        const int n = tid;
        float acc[5] = {0, 0, 0, 0, 0};
        for (int k = 0; k < 64; k++) {
            float wv = W0sT[k * 256 + n];
            #pragma unroll
            for (int g = 0; g < 5; g++) acc[g] = fmaf(sigL[g][k], wv, acc[g]);
        }
        #pragma unroll
        for (int g = 0; g < 5; g++) SL[g][n] = acc[g];
    }
    __syncthreads();

    // ---- sS/dS[g][h] = head-h slice of S dot as0/ad0
    if (tid < 20) {
        int g = tid / 4, h = tid & 3;
        float su = 0.f, sd = 0.f;
        for (int c = 0; c < 64; c++) {
            float sv = SL[g][h * 64 + c];
            su = fmaf(sv, as0[h * 64 + c], su);
            sd = fmaf(sv, ad0[h * 64 + c], sd);
        }
        sSL[g][h] = su; dSL[g][h] = sd;
    }
    __syncthreads();

    // ---- es0/ed0[g][m][h] = (m==0)*sS/dS + act[g][m] . pa0/pd0[h]
    for (int q = tid; q < 320; q += 256) {
        int g = q >> 6, r = q & 63, m = r >> 2, h = r & 3;
        float su = (m == 0) ? sSL[g][h] : 0.f;
        float sd = (m == 0) ? dSL[g][h] : 0.f;
        #pragma unroll
        for (int k = 0; k < 16; k++) {
            float av = actL[g][m][k];
            su = fmaf(av, pa0L[h * 16 + k], su);
            sd = fmaf(av, pd0L[h * 16 + k], sd);
        }
        es0L[g][m][h] = su; ed0L[g][m][h] = sd;
    }
    __syncthreads();

    // ================= per t-group loop =================
    for (int g = 0; g < 5; g++) {
        // alpha0[h][j][s] = softmax_s lrelu(es0[s][h] + ed0[j][h])
        if (tid < 64) {
            int h = tid >> 4, j = tid & 15;
            float ej = ed0L[g][j][h];
            float e[16], m = -1e30f;
            #pragma unroll
            for (int s = 0; s < 16; s++) {
                float x = es0L[g][s][h] + ej;
                x = (x >= 0.f) ? x : 0.2f * x;
                e[s] = x; m = fmaxf(m, x);
            }
            float sum = 0.f;
            #pragma unroll
            for (int s = 0; s < 16; s++) { e[s] = __expf(e[s] - m); sum += e[s]; }
            float inv = 1.f / sum;
            #pragma unroll
            for (int s = 0; s < 16; s++) a0g[h][j][s] = e[s] * inv;
        }
        __syncthreads();

        // d[h][j][k] = sum_s alpha0[h][j][s] * act[s][k]
        #pragma unroll
        for (int q = 0; q < 4; q++) {
            int idx = q * 256 + tid;             // 1024
            int h = idx >> 8, j = (idx >> 4) & 15, k = idx & 15;
            float a = 0.f;
            #pragma unroll
            for (int s = 0; s < 16; s++)
                a = fmaf(a0g[h][j][s], actL[g][s][k], a);
            dL[h][j][k] = a;
        }
        __syncthreads();

        // x1[j][n] = relu(alpha0[h][j][0]*S[n] + d[h][j] . W0aT[:,n] + b0[n])
        {
            const int n = tid, h = n >> 6;
            float sv = SL[g][n], b0v = b0[n];
            float accj[16];
            #pragma unroll
            for (int j = 0; j < 16; j++)
                accj[j] = fmaf(a0g[h][j][0], sv, b0v);
            #pragma unroll
            for (int k = 0; k < 16; k++) {
                float wv = W0aT[k * 256 + n];
                #pragma unroll
                for (int j = 0; j < 16; j++)
                    accj[j] = fmaf(dL[h][j][k], wv, accj[j]);
            }
            #pragma unroll
            for (int j = 0; j < 16; j++)
                x1L[j][n] = fmaxf(accj[j], 0.f);
        }
        __syncthreads();

        // es1[m][h] = x1[m] . u1[h]; ed1[h] = x1[0] . ud1[h]  (k split by p)
        {
            int m = tid >> 4, h = (tid >> 2) & 3, p = tid & 3;
            float a = 0.f;
            for (int kk = 0; kk < 64; kk++) {
                int k = kk * 4 + p;
                a = fmaf(x1L[m][k], u1L[h][k], a);
            }
            espL[m][h][p] = a;
            if (m == 0) {
                float ad = 0.f;
                for (int kk = 0; kk < 64; kk++) {
                    int k = kk * 4 + p;
                    ad = fmaf(x1L[0][k], ud1L[h][k], ad);
                }
                edpL[h][p] = ad;
            }
        }
        __syncthreads();
        if (tid < 64) {
            int m = tid >> 2, h = tid & 3;
            es1L[m][h] = espL[m][h][0] + espL[m][h][1] + espL[m][h][2] + espL[m][h][3];
        }
        if (tid < 4)
            edL[tid] = edpL[tid][0] + edpL[tid][1] + edpL[tid][2] + edpL[tid][3];
        __syncthreads();

        // alpha1[h][s] (dst agent 0)
        if (tid < 4) {
            int h = tid;
            float ej = edL[h];
            float e[16], m = -1e30f;
            #pragma unroll
            for (int s = 0; s < 16; s++) {
                float x = es1L[s][h] + ej;
                x = (x >= 0.f) ? x : 0.2f * x;
                e[s] = x; m = fmaxf(m, x);
            }
            float sum = 0.f;
            #pragma unroll
            for (int s = 0; s < 16; s++) { e[s] = __expf(e[s] - m); sum += e[s]; }
            float inv = 1.f / sum;
            #pragma unroll
            for (int s = 0; s < 16; s++) alpha1L[h][s] = e[s] * inv;
        }
        __syncthreads();

        // z[g][h][k] = sum_s alpha1[h][s] * x1[s][k]
        {
            const int k = tid;
            float xv[16];
            #pragma unroll
            for (int s = 0; s < 16; s++) xv[s] = x1L[s][k];
            #pragma unroll
            for (int h = 0; h < 4; h++) {
                float zv = 0.f;
                #pragma unroll
                for (int s = 0; s < 16; s++)
                    zv = fmaf(alpha1L[h][s], xv[s], zv);
                zL[g][h][k] = zv;
            }
        }
        __syncthreads();   // protect a0g/dL/x1L before next group overwrites
    }

    // ---- final: seq[(b*5+g)][n] = relu(z[g][h(n)] . W1T[:,n] + b1[n])
    {
        const int n = tid, h = n >> 6;
        float b1v = b1[n];
        float acc[5] = {b1v, b1v, b1v, b1v, b1v};
        for (int k = 0; k < 256; k++) {
            float wv = W1T[k * 256 + n];
            #pragma unroll
            for (int g = 0; g < 5; g++)
                acc[g] = fmaf(zL[g][h][k], wv, acc[g]);
        }
        #pragma unroll
        for (int g = 0; g < 5; g++)
            seqf[(b * 5 + g) * 256 + n] = fmaxf(acc[g], 0.f);
    }
}

// ---------------- stage 2: qkv + attention + out_proj + heads ---------------
// One block per 2 batches, 256 threads. All weights transposed (coalesced).
__global__ __launch_bounds__(256) void k_stage2(
    const float* __restrict__ seqf,  // (2560,256)
    const float* __restrict__ wipT,  // [256][768]
    const float* __restrict__ bip,
    const float* __restrict__ wopT,  // [256][256]
    const float* __restrict__ bop,
    const float* __restrict__ whT,   // [256][320]
    const float* __restrict__ bm, const float* __restrict__ blv,
    const float* __restrict__ bb,
    float* __restrict__ out)
{
    __shared__ float sseq[2][5][256];
    __shared__ float kL[2][5][256], vL[2][5][256], qL[2][256];
    __shared__ float ctxL[2][256], featL[2][256];
    __shared__ float beliefL[2][64];
    const int tid = threadIdx.x;
    const int b0 = blockIdx.x * 2;

    // FLAT copy: sseq[gb][t][c] flat index == gb*1280 + t*256 + c == i.
    // (R10 bug: gb = i>>11 split batches at 2048 instead of 1280.)
    {
        float* sflat = &sseq[0][0][0];
        for (int i = tid; i < 2560; i += 256)
            sflat[i] = seqf[b0 * 1280 + i];
    }
    __syncthreads();

    // q (t=4 only)
    {
        const int n = tid;
        float acc[2] = {0, 0};
        for (int k = 0; k < 256; k++) {
            float wv = wipT[k * 768 + n];
            acc[0] = fmaf(sseq[0][4][k], wv, acc[0]);
            acc[1] = fmaf(sseq[1][4][k], wv, acc[1]);
        }
        float bv = bip[n];
        qL[0][n] = acc[0] + bv; qL[1][n] = acc[1] + bv;
    }
    // k and v for all t
    {
        const int n = tid;
        float ak[2][5], av[2][5];
        #pragma unroll
        for (int gb = 0; gb < 2; gb++)
            #pragma unroll
            for (int t = 0; t < 5; t++) { ak[gb][t] = 0.f; av[gb][t] = 0.f; }
        for (int k = 0; k < 256; k++) {
            float wk = wipT[k * 768 + 256 + n];
            float wv = wipT[k * 768 + 512 + n];
            #pragma unroll
            for (int gb = 0; gb < 2; gb++) {
                #pragma unroll
                for (int t = 0; t < 5; t++) {
                    float sv = sseq[gb][t][k];
                    ak[gb][t] = fmaf(wk, sv, ak[gb][t]);
                    av[gb][t] = fmaf(wv, sv, av[gb][t]);
                }
            }
        }
        float bk = bip[256 + n], bv = bip[512 + n];
        #pragma unroll
        for (int gb = 0; gb < 2; gb++)
            #pragma unroll
            for (int t = 0; t < 5; t++) {
                kL[gb][t][n] = ak[gb][t] + bk;
                vL[gb][t][n] = av[gb][t] + bv;
            }
    }
    __syncthreads();

    // attention at q=4 (causal mask constant -> cancels); wave = head
    {
        const int col = tid;
        #pragma unroll
        for (int gb = 0; gb < 2; gb++) {
            float q4 = qL[gb][col];
            float sc[5];
            #pragma unroll
            for (int t = 0; t < 5; t++)
                sc[t] = wave_sum64(q4 * kL[gb][t][col]) * 0.125f;
            float m = sc[0];
            #pragma unroll
            for (int t = 1; t < 5; t++) m = fmaxf(m, sc[t]);
            float p[5], sum = 0.f;
            #pragma unroll
            for (int t = 0; t < 5; t++) { p[t] = __expf(sc[t] - m); sum += p[t]; }
            float inv = 1.f / sum, cv = 0.f;
            #pragma unroll
            for (int t = 0; t < 5; t++) cv = fmaf(p[t], vL[gb][t][col], cv);
            ctxL[gb][col] = cv * inv;
        }
    }
    __syncthreads();

    // out_proj
    {
        const int n = tid;
        float acc[2] = {0, 0};
        for (int k = 0; k < 256; k++) {
            float wv = wopT[k * 256 + n];
            acc[0] = fmaf(ctxL[0][k], wv, acc[0]);
            acc[1] = fmaf(ctxL[1][k], wv, acc[1]);
        }
        float bv = bop[n];
        featL[0][n] = acc[0] + bv; featL[1][n] = acc[1] + bv;
    }
    __syncthreads();

    // heads (mean | logvar | belief-logits), coalesced whT
    for (int j = tid; j < 320; j += 256) {
        float acc[2] = {0, 0};
        for (int k = 0; k < 256; k++) {
            float wv = whT[k * 320 + j];
            acc[0] = fmaf(featL[0][k], wv, acc[0]);
            acc[1] = fmaf(featL[1][k], wv, acc[1]);
        }
        if (j < 128) {
            float bv = bm[j];
            out[(b0 + 0) * 128 + j] = acc[0] + bv;
            out[(b0 + 1) * 128 + j] = acc[1] + bv;
        } else if (j < 256) {
            float bv = blv[j - 128];
            out[65536 + (b0 + 0) * 128 + (j - 128)] = acc[0] + bv;
            out[65536 + (b0 + 1) * 128 + (j - 128)] = acc[1] + bv;
        } else {
            float bv = bb[j - 256];
            beliefL[0][j - 256] = acc[0] + bv;
            beliefL[1][j - 256] = acc[1] + bv;
        }
    }
    __syncthreads();

    // belief softmax: wave 0 -> gb 0, wave 1 -> gb 1
    if (tid < 128) {
        int gb = tid >> 6, lane = tid & 63;
        float lg = beliefL[gb][lane];
        float m = wave_max64(lg);
        float e = __expf(lg - m);
        float s = wave_sum64(e);
        out[131072 + (b0 + gb) * 64 + lane] = e / s;
    }
}

// ---------------------------------------------------------------------------
extern "C" void kernel_launch(void* const* d_in, const int* in_sizes, int n_in,
                              void* d_out, int out_size, void* d_ws, size_t ws_size,
                              hipStream_t stream) {
    const float* sig  = (const float*)d_in[0];
    const float* nact = (const float*)d_in[1];
    const float* w0   = (const float*)d_in[2];
    const float* as0  = (const float*)d_in[3];
    const float* ad0  = (const float*)d_in[4];
    const float* b0   = (const float*)d_in[5];
    const float* w1   = (const float*)d_in[6];
    const float* as1  = (const float*)d_in[7];
    const float* ad1  = (const float*)d_in[8];
    const float* b1   = (const float*)d_in[9];
    const float* wip  = (const float*)d_in[10];
    const float* bip  = (const float*)d_in[11];
    const float* wop  = (const float*)d_in[12];
    const float* bop  = (const float*)d_in[13];
    const float* wm   = (const float*)d_in[14];
    const float* bm   = (const float*)d_in[15];
    const float* wlv  = (const float*)d_in[16];
    const float* blv  = (const float*)d_in[17];
    const float* wb   = (const float*)d_in[18];
    const float* bb   = (const float*)d_in[19];
    // d_in[20] = edge_index (deterministic complete graph) — unused.

    // ws layout (floats). total 1,087,616 f = 4.35 MB
    float* ws    = (float*)d_ws;
    float* seqf  = ws;                 // 655360
    float* tws   = ws + 655360;        // transposes, 430080 total:
    float* W0sT  = tws;                //   16384
    float* W0aT  = tws + 16384;        //   4096
    float* W1T   = tws + 20480;        //   65536
    float* wipT  = tws + 86016;        //   196608
    float* wopT  = tws + 282624;       //   65536
    float* whT   = tws + 348160;       //   81920
    float* u1    = ws + 1085440;       // 1024
    float* ud1   = ws + 1086464;       // 1024
    float* pa0   = ws + 1087488;       // 64
    float* pd0   = ws + 1087552;       // 64

    k_pre1  <<<1680, 256, 0, stream>>>(w0, w1, wip, wop, wm, wlv, wb, tws);
    k_pre2  <<<1, 256, 0, stream>>>(w0, w1, as0, ad0, as1, ad1, u1, ud1, pa0, pd0);
    k_gat   <<<512, 256, 0, stream>>>(sig, nact, W0sT, W0aT, W1T,
                                      u1, ud1, pa0, pd0, as0, ad0, b0, b1, seqf);
    k_stage2<<<256, 256, 0, stream>>>(seqf, wipT, bip, wopT, bop, whT,
                                      bm, blv, bb, (float*)d_out);
}

// Round 12
// 205.166 us; speedup vs baseline: 12.5838x; 1.1519x over previous
//
#include <hip/hip_runtime.h>
#include <hip/hip_bf16.h>

// T=5 B=512 NA=16 S=64 A=16 HID=64 H=4 FD=256 LAT=128 N=8192 FIN=80
// Inputs fp32, output fp32. edge graph = complete per 16-agent batch (ignored
// input). seq = x[::16] (dst agent-0 only). attention query only at t=4.
//
// R12 vs R11 (236 us): profile showed k_stage2 #1 at 78 us with occupancy
// 10.9% (grid 256 -> 1 block/CU x 4 waves) -> wave-starved latency bound.
//  1. k_stage2 -> 768 threads (12 waves): thread = (q|k|v kind, col); k/v
//     threads carry 10 accs (10 FMA per coalesced load). Same LDS (37 KB).
//  2. pre1+pre2 merged into one kernel (block 1680 does the reductions) --
//     ~60 us of the total was inter-kernel gaps (4-kernel graph).
//  3. k_gat untouched (R11 verbatim) -- will now show in top-5 for R13.

__device__ __forceinline__ float wave_sum64(float v) {
    #pragma unroll
    for (int off = 32; off > 0; off >>= 1) v += __shfl_xor(v, off, 64);
    return v;
}
__device__ __forceinline__ float wave_max64(float v) {
    #pragma unroll
    for (int off = 32; off > 0; off >>= 1) v = fmaxf(v, __shfl_xor(v, off, 64));
    return v;
}

// ---------------- prologue: transposes + u1/ud1/pa0/pd0 (merged) ------------
// blocks 0..1679: transposes into tws; block 1680: attention-vector folds.
// tws segments (float offsets): W0sT[64][256] | W0aT[16][256] | W1T[256][256]
// | wipT[256][768] | wopT[256][256] | whT[256][320]
__global__ __launch_bounds__(256) void k_pre(
    const float* __restrict__ w0, const float* __restrict__ w1,
    const float* __restrict__ wip, const float* __restrict__ wop,
    const float* __restrict__ wm, const float* __restrict__ wlv,
    const float* __restrict__ wb,
    const float* __restrict__ as0, const float* __restrict__ ad0,
    const float* __restrict__ as1, const float* __restrict__ ad1,
    float* __restrict__ tws,
    float* __restrict__ u1, float* __restrict__ ud1,
    float* __restrict__ pa0, float* __restrict__ pd0)
{
    const int tid = threadIdx.x;
    if (blockIdx.x < 1680) {
        int i = blockIdx.x * 256 + tid;          // 1680*256 = 430080 exact
        float v;
        if (i < 16384) {                         // W0sT[k][n] = w0[n][k]
            int k = i >> 8, n = i & 255;
            v = w0[n * 80 + k];
        } else if (i < 20480) {                  // W0aT[k][n] = w0[n][64+k]
            int j = i - 16384; int k = j >> 8, n = j & 255;
            v = w0[n * 80 + 64 + k];
        } else if (i < 86016) {                  // W1T[k][n] = w1[n][k]
            int j = i - 20480; int k = j >> 8, n = j & 255;
            v = w1[n * 256 + k];
        } else if (i < 282624) {                 // wipT[k][n'] = wip[n'][k]
            int j = i - 86016; int k = j / 768, n = j - k * 768;
            v = wip[n * 256 + k];
        } else if (i < 348160) {                 // wopT[k][n] = wop[n][k]
            int j = i - 282624; int k = j >> 8, n = j & 255;
            v = wop[n * 256 + k];
        } else {                                 // whT[k][j]: mean|logvar|belief
            int j = i - 348160; int k = j / 320, o = j - k * 320;
            if (o < 128)      v = wm[o * 256 + k];
            else if (o < 256) v = wlv[(o - 128) * 256 + k];
            else              v = wb[(o - 256) * 256 + k];
        }
        tws[i] = v;
        return;
    }
    // block 1680: u1[h][k] = sum_c as1[h][c]*w1[(h*64+c)][k]; ud1 with ad1
    for (int q = 0; q < 4; q++) {
        int idx = q * 256 + tid;                 // 1024
        int h = idx >> 8, k = idx & 255;
        float su = 0.f, sd = 0.f;
        for (int c = 0; c < 64; c++) {
            float wv = w1[(h * 64 + c) * 256 + k];
            su = fmaf(as1[h * 64 + c], wv, su);
            sd = fmaf(ad1[h * 64 + c], wv, sd);
        }
        u1[idx] = su; ud1[idx] = sd;
    }
    // pa0[h][k<16] = sum_c as0[h][c]*w0[(h*64+c)][64+k]; pd0 with ad0
    if (tid < 64) {
        int h = tid >> 4, k = tid & 15;
        float su = 0.f, sd = 0.f;
        for (int c = 0; c < 64; c++) {
            float wv = w0[(h * 64 + c) * 80 + 64 + k];
            su = fmaf(as0[h * 64 + c], wv, su);
            sd = fmaf(ad0[h * 64 + c], wv, sd);
        }
        pa0[tid] = su; pd0[tid] = sd;
    }
}

// ---------------- stage 1: fused 2-layer GAT, one block per b (R11 verbatim) -
__global__ __launch_bounds__(256) void k_gat(
    const float* __restrict__ sig,   // (T,B,64)
    const float* __restrict__ nact,  // (T,B,256)
    const float* __restrict__ W0sT,  // [64][256]
    const float* __restrict__ W0aT,  // [16][256]
    const float* __restrict__ W1T,   // [256][256]
    const float* __restrict__ u1g, const float* __restrict__ ud1g,   // [4][256]
    const float* __restrict__ pa0g, const float* __restrict__ pd0g,  // [4][16]
    const float* __restrict__ as0, const float* __restrict__ ad0,
    const float* __restrict__ b0, const float* __restrict__ b1,
    float* __restrict__ seqf)        // (2560,256)
{
    __shared__ float sigL[5][64];
    __shared__ float actL[5][16][16];
    __shared__ float SL[5][258];
    __shared__ float u1L[4][256], ud1L[4][256];
    __shared__ float pa0L[64], pd0L[64];
    __shared__ float sSL[5][4], dSL[5][4];
    __shared__ float es0L[5][16][4], ed0L[5][16][4];
    __shared__ float a0g[4][16][16];             // per-group alpha0 [h][j][s]
    __shared__ float dL[4][16][16];              // per-group d [h][j][k]
    __shared__ float x1L[16][258];               // per-group x1
    __shared__ float espL[16][4][4];             // es1 partials [m][h][p]
    __shared__ float edpL[4][4];
    __shared__ float es1L[16][4];
    __shared__ float edL[4];
    __shared__ float alpha1L[4][16];
    __shared__ float zL[5][4][258];              // z per group/head

    const int tid = threadIdx.x;
    const int b = blockIdx.x;

    for (int i = tid; i < 320; i += 256)
        sigL[i >> 6][i & 63] = sig[((i >> 6) * 512 + b) * 64 + (i & 63)];
    for (int i = tid; i < 1280; i += 256) {
        int g = i >> 8, r = i & 255;
        actL[g][r >> 4][r & 15] = nact[(g * 512 + b) * 256 + r];
    }
    for (int q = 0; q < 4; q++) {
        int idx = q * 256 + tid;
        u1L[idx >> 8][idx & 255] = u1g[idx];
        ud1L[idx >> 8][idx & 255] = ud1g[idx];
    }
    if (tid < 64) { pa0L[tid] = pa0g[tid]; pd0L[tid] = pd0g[tid]; }
    __syncthreads();

    // S[g][n] = sum_k sig[g][k] * W0sT[k][n]
    {
        const int n = tid;
        float acc[5] = {0, 0, 0, 0, 0};
        for (int k = 0; k < 64; k++) {
            float wv = W0sT[k * 256 + n];
            #pragma unroll
            for (int g = 0; g < 5; g++) acc[g] = fmaf(sigL[g][k], wv, acc[g]);
        }
        #pragma unroll
        for (int g = 0; g < 5; g++) SL[g][n] = acc[g];
    }
    __syncthreads();

    // sS/dS[g][h]
    if (tid < 20) {
        int g = tid / 4, h = tid & 3;
        float su = 0.f, sd = 0.f;
        for (int c = 0; c < 64; c++) {
            float sv = SL[g][h * 64 + c];
            su = fmaf(sv, as0[h * 64 + c], su);
            sd = fmaf(sv, ad0[h * 64 + c], sd);
        }
        sSL[g][h] = su; dSL[g][h] = sd;
    }
    __syncthreads();

    // es0/ed0[g][m][h]
    for (int q = tid; q < 320; q += 256) {
        int g = q >> 6, r = q & 63, m = r >> 2, h = r & 3;
        float su = (m == 0) ? sSL[g][h] : 0.f;
        float sd = (m == 0) ? dSL[g][h] : 0.f;
        #pragma unroll
        for (int k = 0; k < 16; k++) {
            float av = actL[g][m][k];
            su = fmaf(av, pa0L[h * 16 + k], su);
            sd = fmaf(av, pd0L[h * 16 + k], sd);
        }
        es0L[g][m][h] = su; ed0L[g][m][h] = sd;
    }
    __syncthreads();

    for (int g = 0; g < 5; g++) {
        if (tid < 64) {
            int h = tid >> 4, j = tid & 15;
            float ej = ed0L[g][j][h];
            float e[16], m = -1e30f;
            #pragma unroll
            for (int s = 0; s < 16; s++) {
                float x = es0L[g][s][h] + ej;
                x = (x >= 0.f) ? x : 0.2f * x;
                e[s] = x; m = fmaxf(m, x);
            }
            float sum = 0.f;
            #pragma unroll
            for (int s = 0; s < 16; s++) { e[s] = __expf(e[s] - m); sum += e[s]; }
            float inv = 1.f / sum;
            #pragma unroll
            for (int s = 0; s < 16; s++) a0g[h][j][s] = e[s] * inv;
        }
        __syncthreads();

        #pragma unroll
        for (int q = 0; q < 4; q++) {
            int idx = q * 256 + tid;
            int h = idx >> 8, j = (idx >> 4) & 15, k = idx & 15;
            float a = 0.f;
            #pragma unroll
            for (int s = 0; s < 16; s++)
                a = fmaf(a0g[h][j][s], actL[g][s][k], a);
            dL[h][j][k] = a;
        }
        __syncthreads();

        {
            const int n = tid, h = n >> 6;
            float sv = SL[g][n], b0v = b0[n];
            float accj[16];
            #pragma unroll
            for (int j = 0; j < 16; j++)
                accj[j] = fmaf(a0g[h][j][0], sv, b0v);
            #pragma unroll
            for (int k = 0; k < 16; k++) {
                float wv = W0aT[k * 256 + n];
                #pragma unroll
                for (int j = 0; j < 16; j++)
                    accj[j] = fmaf(dL[h][j][k], wv, accj[j]);
            }
            #pragma unroll
            for (int j = 0; j < 16; j++)
                x1L[j][n] = fmaxf(accj[j], 0.f);
        }
        __syncthreads();

        {
            int m = tid >> 4, h = (tid >> 2) & 3, p = tid & 3;
            float a = 0.f;
            for (int kk = 0; kk < 64; kk++) {
                int k = kk * 4 + p;
                a = fmaf(x1L[m][k], u1L[h][k], a);
            }
            espL[m][h][p] = a;
            if (m == 0) {
                float ad = 0.f;
                for (int kk = 0; kk < 64; kk++) {
                    int k = kk * 4 + p;
                    ad = fmaf(x1L[0][k], ud1L[h][k], ad);
                }
                edpL[h][p] = ad;
            }
        }
        __syncthreads();
        if (tid < 64) {
            int m = tid >> 2, h = tid & 3;
            es1L[m][h] = espL[m][h][0] + espL[m][h][1] + espL[m][h][2] + espL[m][h][3];
        }
        if (tid < 4)
            edL[tid] = edpL[tid][0] + edpL[tid][1] + edpL[tid][2] + edpL[tid][3];
        __syncthreads();

        if (tid < 4) {
            int h = tid;
            float ej = edL[h];
            float e[16], m = -1e30f;
            #pragma unroll
            for (int s = 0; s < 16; s++) {
                float x = es1L[s][h] + ej;
                x = (x >= 0.f) ? x : 0.2f * x;
                e[s] = x; m = fmaxf(m, x);
            }
            float sum = 0.f;
            #pragma unroll
            for (int s = 0; s < 16; s++) { e[s] = __expf(e[s] - m); sum += e[s]; }
            float inv = 1.f / sum;
            #pragma unroll
            for (int s = 0; s < 16; s++) alpha1L[h][s] = e[s] * inv;
        }
        __syncthreads();

        {
            const int k = tid;
            float xv[16];
            #pragma unroll
            for (int s = 0; s < 16; s++) xv[s] = x1L[s][k];
            #pragma unroll
            for (int h = 0; h < 4; h++) {
                float zv = 0.f;
                #pragma unroll
                for (int s = 0; s < 16; s++)
                    zv = fmaf(alpha1L[h][s], xv[s], zv);
                zL[g][h][k] = zv;
            }
        }
        __syncthreads();
    }

    // final: seq[(b*5+g)][n] = relu(z[g][h(n)] . W1T[:,n] + b1[n])
    {
        const int n = tid, h = n >> 6;
        float b1v = b1[n];
        float acc[5] = {b1v, b1v, b1v, b1v, b1v};
        for (int k = 0; k < 256; k++) {
            float wv = W1T[k * 256 + n];
            #pragma unroll
            for (int g = 0; g < 5; g++)
                acc[g] = fmaf(zL[g][h][k], wv, acc[g]);
        }
        #pragma unroll
        for (int g = 0; g < 5; g++)
            seqf[(b * 5 + g) * 256 + n] = fmaxf(acc[g], 0.f);
    }
}

// ---------------- stage 2: qkv + attention + out_proj + heads ---------------
// One block per 2 batches, 768 threads (12 waves): thread = (kind q|k|v, col).
__global__ __launch_bounds__(768) void k_stage2(
    const float* __restrict__ seqf,  // (2560,256)
    const float* __restrict__ wipT,  // [256][768]
    const float* __restrict__ bip,
    const float* __restrict__ wopT,  // [256][256]
    const float* __restrict__ bop,
    const float* __restrict__ whT,   // [256][320]
    const float* __restrict__ bm, const float* __restrict__ blv,
    const float* __restrict__ bb,
    float* __restrict__ out)
{
    __shared__ float sseq[2][5][256];
    __shared__ float kL[2][5][256], vL[2][5][256], qL[2][256];
    __shared__ float ctxL[2][256], featL[2][256];
    __shared__ float beliefL[2][64];
    const int tid = threadIdx.x;
    const int b0 = blockIdx.x * 2;

    {   // flat copy (batch boundary at 1280)
        float* sflat = &sseq[0][0][0];
        for (int i = tid; i < 2560; i += 768)
            sflat[i] = seqf[b0 * 1280 + i];
    }
    __syncthreads();

    // qkv: kind 0 -> q (t=4, both gb); kind 1 -> k (10 accs); kind 2 -> v
    {
        const int kind = tid >> 8, n = tid & 255;
        if (kind == 0) {
            float a0 = 0.f, a1 = 0.f;
            for (int k = 0; k < 256; k++) {
                float wv = wipT[k * 768 + n];
                a0 = fmaf(sseq[0][4][k], wv, a0);
                a1 = fmaf(sseq[1][4][k], wv, a1);
            }
            float bv = bip[n];
            qL[0][n] = a0 + bv; qL[1][n] = a1 + bv;
        } else {
            const float* wcol = wipT + kind * 256 + n;     // stride 768
            float acc[2][5];
            #pragma unroll
            for (int gb = 0; gb < 2; gb++)
                #pragma unroll
                for (int t = 0; t < 5; t++) acc[gb][t] = 0.f;
            for (int k = 0; k < 256; k++) {
                float wv = wcol[k * 768];
                #pragma unroll
                for (int gb = 0; gb < 2; gb++) {
                    #pragma unroll
                    for (int t = 0; t < 5; t++)
                        acc[gb][t] = fmaf(sseq[gb][t][k], wv, acc[gb][t]);
                }
            }
            float bv = bip[kind * 256 + n];
            float* dst = (kind == 1) ? &kL[0][0][0] : &vL[0][0][0];
            #pragma unroll
            for (int gb = 0; gb < 2; gb++)
                #pragma unroll
                for (int t = 0; t < 5; t++)
                    dst[gb * 1280 + t * 256 + n] = acc[gb][t] + bv;
        }
    }
    __syncthreads();

    // attention at q=4 (causal mask constant -> cancels); 64-lane col groups
    if (tid < 512) {
        const int gb = tid >> 8, col = tid & 255;
        float q4 = qL[gb][col];
        float sc[5];
        #pragma unroll
        for (int t = 0; t < 5; t++)
            sc[t] = wave_sum64(q4 * kL[gb][t][col]) * 0.125f;
        float m = sc[0];
        #pragma unroll
        for (int t = 1; t < 5; t++) m = fmaxf(m, sc[t]);
        float p[5], sum = 0.f;
        #pragma unroll
        for (int t = 0; t < 5; t++) { p[t] = __expf(sc[t] - m); sum += p[t]; }
        float inv = 1.f / sum, cv = 0.f;
        #pragma unroll
        for (int t = 0; t < 5; t++) cv = fmaf(p[t], vL[gb][t][col], cv);
        ctxL[gb][col] = cv * inv;
    }
    __syncthreads();

    // out_proj
    if (tid < 512) {
        const int gb = tid >> 8, n = tid & 255;
        float acc = 0.f;
        for (int k = 0; k < 256; k++)
            acc = fmaf(ctxL[gb][k], wopT[k * 256 + n], acc);
        featL[gb][n] = acc + bop[n];
    }
    __syncthreads();

    // heads: j in [0,320) for both gb (tid < 640)
    if (tid < 640) {
        const int gb = tid / 320, j = tid - gb * 320;
        float acc = 0.f;
        for (int k = 0; k < 256; k++)
            acc = fmaf(featL[gb][k], whT[k * 320 + j], acc);
        if (j < 128) {
            out[(b0 + gb) * 128 + j] = acc + bm[j];
        } else if (j < 256) {
            out[65536 + (b0 + gb) * 128 + (j - 128)] = acc + blv[j - 128];
        } else {
            beliefL[gb][j - 256] = acc + bb[j - 256];
        }
    }
    __syncthreads();

    // belief softmax: wave 0 -> gb 0, wave 1 -> gb 1
    if (tid < 128) {
        int gb = tid >> 6, lane = tid & 63;
        float lg = beliefL[gb][lane];
        float m = wave_max64(lg);
        float e = __expf(lg - m);
        float s = wave_sum64(e);
        out[131072 + (b0 + gb) * 64 + lane] = e / s;
    }
}

// ---------------------------------------------------------------------------
extern "C" void kernel_launch(void* const* d_in, const int* in_sizes, int n_in,
                              void* d_out, int out_size, void* d_ws, size_t ws_size,
                              hipStream_t stream) {
    const float* sig  = (const float*)d_in[0];
    const float* nact = (const float*)d_in[1];
    const float* w0   = (const float*)d_in[2];
    const float* as0  = (const float*)d_in[3];
    const float* ad0  = (const float*)d_in[4];
    const float* b0   = (const float*)d_in[5];
    const float* w1   = (const float*)d_in[6];
    const float* as1  = (const float*)d_in[7];
    const float* ad1  = (const float*)d_in[8];
    const float* b1   = (const float*)d_in[9];
    const float* wip  = (const float*)d_in[10];
    const float* bip  = (const float*)d_in[11];
    const float* wop  = (const float*)d_in[12];
    const float* bop  = (const float*)d_in[13];
    const float* wm   = (const float*)d_in[14];
    const float* bm   = (const float*)d_in[15];
    const float* wlv  = (const float*)d_in[16];
    const float* blv  = (const float*)d_in[17];
    const float* wb   = (const float*)d_in[18];
    const float* bb   = (const float*)d_in[19];
    // d_in[20] = edge_index (deterministic complete graph) — unused.

    // ws layout (floats). total 1,087,616 f = 4.35 MB
    float* ws    = (float*)d_ws;
    float* seqf  = ws;                 // 655360
    float* tws   = ws + 655360;        // transposes, 430080 total:
    float* W0sT  = tws;                //   16384
    float* W0aT  = tws + 16384;        //   4096
    float* W1T   = tws + 20480;        //   65536
    float* wipT  = tws + 86016;        //   196608
    float* wopT  = tws + 282624;       //   65536
    float* whT   = tws + 348160;       //   81920
    float* u1    = ws + 1085440;       // 1024
    float* ud1   = ws + 1086464;       // 1024
    float* pa0   = ws + 1087488;       // 64
    float* pd0   = ws + 1087552;       // 64

    k_pre   <<<1681, 256, 0, stream>>>(w0, w1, wip, wop, wm, wlv, wb,
                                       as0, ad0, as1, ad1,
                                       tws, u1, ud1, pa0, pd0);
    k_gat   <<<512, 256, 0, stream>>>(sig, nact, W0sT, W0aT, W1T,
                                      u1, ud1, pa0, pd0, as0, ad0, b0, b1, seqf);
    k_stage2<<<256, 768, 0, stream>>>(seqf, wipT, bip, wopT, bop, whT,
                                      bm, blv, bb, (float*)d_out);
}